// Round 6
// baseline (153.993 us; speedup 1.0000x reference)
//
#include <hip/hip_runtime.h>
#include <hip/hip_bf16.h>

#define NN 30000
#define DIM 128
#define NT 6
#define NE 480000
#define NSLOT 1024
#define NSEG (NT*3*NSLOT)   // 18432
#define SEGCAP 96
#define NBM ((NN+31)/32)    // 938

typedef __attribute__((ext_vector_type(8))) short bf16x8;
typedef __attribute__((ext_vector_type(4))) float f32x4;

__device__ __forceinline__ float lrelu(float x){ return x > 0.f ? x : 0.2f*x; }
__device__ __forceinline__ unsigned short f2b(float f){
    unsigned u = __float_as_uint(f);
    u = (u + 0x7FFFu + ((u>>16)&1u)) >> 16;
    return (unsigned short)u;
}
__device__ __forceinline__ float b2f(unsigned short b){
    return __uint_as_float(((unsigned)b)<<16);
}

// blocks 0..3 -> Wp,Wc,Wl,Wr transposed bf16 (+wa for 0,1); block 4 -> slotmap
__global__ void k_prep(const float* __restrict__ Wp, const float* __restrict__ Wc,
        const float* __restrict__ Wl, const float* __restrict__ Wr,
        const float* __restrict__ aspv, const float* __restrict__ adpv,
        const float* __restrict__ ascv, const float* __restrict__ adcv,
        const int* __restrict__ s, int* __restrict__ n2s, unsigned* __restrict__ bm,
        float* __restrict__ wa, unsigned short* __restrict__ WT4){
    int m = blockIdx.x, t = threadIdx.x;
    if (m == 4){
        for (int i = t; i < NSLOT; i += 256){
            int v = s[i];
            atomicMin(&n2s[v], i);
            atomicOr(&bm[v>>5], 1u << (v&31));
        }
        return;
    }
    const float* W = (m==0) ? Wp : (m==1) ? Wc : (m==2) ? Wl : Wr;
    unsigned short* WT = WT4 + (size_t)m*DIM*DIM;
    if (m < 2 && t < DIM){
        const float* avs = m ? ascv : aspv;
        const float* avd = m ? adcv : adpv;
        float* wab = wa + m*2*DIM;
        float sv = 0.f, dv = 0.f;
        for (int n = 0; n < DIM; n++){
            float w = W[t*DIM + n];
            sv += w*avs[n]; dv += w*avd[n];
        }
        wab[t] = sv; wab[DIM + t] = dv;
    }
    for (int j = t; j < DIM*DIM; j += blockDim.x){
        int n = j >> 7, k = j & 127;
        WT[n*DIM + k] = f2b(W[k*DIM + n]);
    }
}

// wave per node: cast X row to bf16 + 4 attention scalars (f32 via wa)
__global__ __launch_bounds__(256) void k_cast(const float* __restrict__ X,
        const float* __restrict__ wa, unsigned* __restrict__ Xbf,
        float* __restrict__ asp, float* __restrict__ adp,
        float* __restrict__ asc, float* __restrict__ adc){
    int gw = (blockIdx.x*blockDim.x + threadIdx.x) >> 6;
    int lane = threadIdx.x & 63;
    if (gw >= NN) return;
    float2 x = *(const float2*)&X[(size_t)gw*DIM + lane*2];
    Xbf[(size_t)gw*(DIM/2) + lane] = (unsigned)f2b(x.x) | ((unsigned)f2b(x.y) << 16);
    float sp = x.x*wa[2*lane]     + x.y*wa[2*lane+1];
    float dp = x.x*wa[128+2*lane] + x.y*wa[128+2*lane+1];
    float sc = x.x*wa[256+2*lane] + x.y*wa[256+2*lane+1];
    float dc = x.x*wa[384+2*lane] + x.y*wa[384+2*lane+1];
    #pragma unroll
    for (int off = 32; off; off >>= 1){
        sp += __shfl_xor(sp, off); dp += __shfl_xor(dp, off);
        sc += __shfl_xor(sc, off); dc += __shfl_xor(dc, off);
    }
    if (lane == 0){ asp[gw] = sp; adp[gw] = dp; asc[gw] = sc; adc[gw] = dc; }
}

// MFMA GEMM: wave = 16 rows x 128 cols, both P and C matrices; bf16 out.
__global__ __launch_bounds__(256) void k_gemm(const unsigned short* __restrict__ Xbf,
        const unsigned short* __restrict__ WT4,
        unsigned short* __restrict__ hpb, unsigned short* __restrict__ hcb){
    const unsigned short* WTp = WT4;
    const unsigned short* WTc = WT4 + DIM*DIM;
    int wid = threadIdx.x >> 6, lane = threadIdx.x & 63;
    int r0 = blockIdx.x*64 + wid*16;
    int arow = r0 + (lane & 15); if (arow > NN-1) arow = NN-1;
    int g = lane >> 4;
    bf16x8 A[4];
    #pragma unroll
    for (int ks = 0; ks < 4; ks++)
        A[ks] = *(const bf16x8*)&Xbf[(size_t)arow*DIM + ks*32 + g*8];
    int cl = lane & 15;
    #pragma unroll
    for (int ct = 0; ct < 8; ct++){
        f32x4 aP = {0.f,0.f,0.f,0.f}, aC = {0.f,0.f,0.f,0.f};
        int bcol = ct*16 + cl;
        #pragma unroll
        for (int ks = 0; ks < 4; ks++){
            bf16x8 bP = *(const bf16x8*)&WTp[bcol*DIM + ks*32 + g*8];
            bf16x8 bC = *(const bf16x8*)&WTc[bcol*DIM + ks*32 + g*8];
            aP = __builtin_amdgcn_mfma_f32_16x16x32_bf16(A[ks], bP, aP, 0, 0, 0);
            aC = __builtin_amdgcn_mfma_f32_16x16x32_bf16(A[ks], bC, aC, 0, 0, 0);
        }
        #pragma unroll
        for (int r = 0; r < 4; r++){
            int row = r0 + g*4 + r;
            if (row < NN){
                hpb[(size_t)row*DIM + bcol] = f2b(aP[r]);
                hcb[(size_t)row*DIM + bcol] = f2b(aC[r]);
            }
        }
    }
}

// CSR build: grid (118, 18); 4 independent int4 dst loads upfront, tests, then match tail
__global__ __launch_bounds__(256) void k_build(const int* __restrict__ EI,
        const unsigned* __restrict__ bm, const int* __restrict__ n2s,
        int* __restrict__ cnt, int* __restrict__ csr){
    __shared__ unsigned bms[NBM];
    for (int j = threadIdx.x; j < NBM; j += 256) bms[j] = bm[j];
    __syncthreads();
    const int Q = NE/4;                  // 120000 int4 per row
    const int G = gridDim.x*blockDim.x;  // threads per row
    int row = blockIdx.y;
    const int4* dstp = (const int4*)(EI + (size_t)(2*row+1)*NE);
    const int*  srcs = EI + (size_t)(2*row)*NE;
    int tid = blockIdx.x*blockDim.x + threadIdx.x;
    int base = row*NSLOT;
    int4 d[4];
    int ix[4];
    bool va[4];
    #pragma unroll
    for (int u = 0; u < 4; u++){
        ix[u] = tid + u*G;
        va[u] = ix[u] < Q;
        d[u] = make_int4(0,0,0,0);
        if (va[u]) d[u] = dstp[ix[u]];
    }
    unsigned mm[4][4];
    #pragma unroll
    for (int u = 0; u < 4; u++){
        mm[u][0] = va[u] ? ((bms[d[u].x>>5] >> (d[u].x&31)) & 1u) : 0u;
        mm[u][1] = va[u] ? ((bms[d[u].y>>5] >> (d[u].y&31)) & 1u) : 0u;
        mm[u][2] = va[u] ? ((bms[d[u].z>>5] >> (d[u].z&31)) & 1u) : 0u;
        mm[u][3] = va[u] ? ((bms[d[u].w>>5] >> (d[u].w&31)) & 1u) : 0u;
    }
    #pragma unroll
    for (int u = 0; u < 4; u++){
        int dv0 = d[u].x, dv1 = d[u].y, dv2 = d[u].z, dv3 = d[u].w;
        if (mm[u][0]){ int sl = n2s[dv0]; int p = atomicAdd(&cnt[base+sl],1); if (p < SEGCAP) csr[(size_t)(base+sl)*SEGCAP+p] = srcs[ix[u]*4+0]; }
        if (mm[u][1]){ int sl = n2s[dv1]; int p = atomicAdd(&cnt[base+sl],1); if (p < SEGCAP) csr[(size_t)(base+sl)*SEGCAP+p] = srcs[ix[u]*4+1]; }
        if (mm[u][2]){ int sl = n2s[dv2]; int p = atomicAdd(&cnt[base+sl],1); if (p < SEGCAP) csr[(size_t)(base+sl)*SEGCAP+p] = srcs[ix[u]*4+2]; }
        if (mm[u][3]){ int sl = n2s[dv3]; int p = atomicAdd(&cnt[base+sl],1); if (p < SEGCAP) csr[(size_t)(base+sl)*SEGCAP+p] = srcs[ix[u]*4+3]; }
    }
}

// wave per segment: g<2 -> GAT (p/c), g==2 -> SAGE neighbor-mean
__global__ __launch_bounds__(256) void k_aggr(
        const unsigned* __restrict__ hpb, const unsigned* __restrict__ hcb,
        const unsigned* __restrict__ Xbf,
        const float* __restrict__ asp, const float* __restrict__ adp,
        const float* __restrict__ asc, const float* __restrict__ adc,
        const float* __restrict__ bp, const float* __restrict__ bc,
        const int* __restrict__ s, const int* __restrict__ cnt, const int* __restrict__ csr,
        float* __restrict__ bufP, float* __restrict__ bufC, unsigned* __restrict__ meanb){
    int gw = (blockIdx.x*blockDim.x + threadIdx.x) >> 6;
    int lane = threadIdx.x & 63;
    if (gw >= NSEG) return;
    int slot = gw & (NSLOT-1);
    int tg = gw >> 10;
    int g = tg % 3, t = tg / 3;
    int n = cnt[gw]; if (n > SEGCAP) n = SEGCAP;
    const int* lst = csr + (size_t)gw*SEGCAP;
    if (g == 2){
        float m0 = 0.f, m1 = 0.f;
        for (int j = 0; j < n; j++){
            unsigned pk = Xbf[(size_t)lst[j]*(DIM/2) + lane];
            m0 += b2f((unsigned short)(pk & 0xFFFF));
            m1 += b2f((unsigned short)(pk >> 16));
        }
        float c = (float)n; if (c < 1.f) c = 1.f;
        float invc = 1.f/c;
        meanb[(size_t)(t*NSLOT+slot)*(DIM/2) + lane] =
            (unsigned)f2b(m0*invc) | ((unsigned)f2b(m1*invc) << 16);
        return;
    }
    const unsigned* h = g ? hcb : hpb;
    const float* as = g ? asc : asp;
    const float* ad = g ? adc : adp;
    const float* b  = g ? bc  : bp;
    int v = s[slot];
    float adv = ad[v];
    float eself = lrelu(as[v] + adv);
    float m = eself;
    for (int j = lane; j < n; j += 64)
        m = fmaxf(m, lrelu(as[lst[j]] + adv));
    #pragma unroll
    for (int off = 32; off; off >>= 1) m = fmaxf(m, __shfl_xor(m, off));
    float pself = __expf(eself - m);
    float denom = pself;
    unsigned pkv = h[(size_t)v*(DIM/2) + lane];
    float a0 = pself * b2f((unsigned short)(pkv & 0xFFFF));
    float a1 = pself * b2f((unsigned short)(pkv >> 16));
    for (int j = 0; j < n; j++){
        int src = lst[j];
        float p = __expf(lrelu(as[src] + adv) - m);
        denom += p;
        unsigned pk = h[(size_t)src*(DIM/2) + lane];
        a0 += p * b2f((unsigned short)(pk & 0xFFFF));
        a1 += p * b2f((unsigned short)(pk >> 16));
    }
    float inv = 1.f/denom;
    float* ob = g ? bufC : bufP;
    ob[(size_t)(t*NSLOT+slot)*DIM + 2*lane]   = a0*inv + b[2*lane];
    ob[(size_t)(t*NSLOT+slot)*DIM + 2*lane+1] = a1*inv + b[2*lane+1];
}

// blocks 0..95: meanb@WlT -> mWl; blocks 96..111: Xbf[s[slot]]@WrT -> xWr
__global__ __launch_bounds__(256) void k_sgemm(const unsigned short* __restrict__ meanb,
        const unsigned* __restrict__ Xbf, const unsigned short* __restrict__ WT4,
        const int* __restrict__ s,
        float* __restrict__ mWl, float* __restrict__ xWr){
    int task = (blockIdx.x >= 96);
    int blk  = task ? (blockIdx.x - 96) : blockIdx.x;
    const unsigned short* WT = WT4 + (size_t)(task ? 3 : 2)*DIM*DIM;
    float* out = task ? xWr : mWl;
    int rows = task ? NSLOT : NT*NSLOT;
    int wid = threadIdx.x >> 6, lane = threadIdx.x & 63;
    int r0 = blk*64 + wid*16;
    int ar = r0 + (lane & 15); if (ar > rows-1) ar = rows-1;
    int g = lane >> 4;
    const unsigned short* Arow = task
        ? (const unsigned short*)(Xbf + (size_t)s[ar]*(DIM/2))
        : (meanb + (size_t)ar*DIM);
    bf16x8 Af[4];
    #pragma unroll
    for (int ks = 0; ks < 4; ks++)
        Af[ks] = *(const bf16x8*)&Arow[ks*32 + g*8];
    int cl = lane & 15;
    #pragma unroll
    for (int ct = 0; ct < 8; ct++){
        f32x4 acc = {0.f,0.f,0.f,0.f};
        int bcol = ct*16 + cl;
        #pragma unroll
        for (int ks = 0; ks < 4; ks++){
            bf16x8 bF = *(const bf16x8*)&WT[bcol*DIM + ks*32 + g*8];
            acc = __builtin_amdgcn_mfma_f32_16x16x32_bf16(Af[ks], bF, acc, 0, 0, 0);
        }
        #pragma unroll
        for (int r = 0; r < 4; r++){
            int row = r0 + g*4 + r;
            if (row < rows) out[(size_t)row*DIM + bcol] = acc[r];
        }
    }
}

__global__ void k_gather(const int* __restrict__ s, const int* __restrict__ n2s,
                         const float* __restrict__ bufP, const float* __restrict__ bufC,
                         const float* __restrict__ mWl, const float* __restrict__ xWr,
                         const float* __restrict__ bl, const float* __restrict__ br,
                         float* __restrict__ out){
    int i = blockIdx.x*blockDim.x + threadIdx.x;
    if (i >= NT*NSLOT*DIM) return;
    int d = i & 127;
    int r = (i >> 7) & (NSLOT-1);
    int t = i >> 17;
    int rep = n2s[s[r]];
    size_t j = (size_t)(t*NSLOT + rep)*DIM + d;
    out[i] = (bufP[j] + bufC[j] + mWl[j] + xWr[(size_t)rep*DIM + d] + bl[d] + br[d]) * (1.f/3.f);
}

extern "C" void kernel_launch(void* const* d_in, const int* in_sizes, int n_in,
                              void* d_out, int out_size, void* d_ws, size_t ws_size,
                              hipStream_t stream) {
    const int*   s    = (const int*)d_in[0];
    const int*   EI   = (const int*)d_in[3];
    const float* X    = (const float*)d_in[4];
    const float* Wp   = (const float*)d_in[5];
    const float* aspv = (const float*)d_in[6];
    const float* adpv = (const float*)d_in[7];
    const float* bp   = (const float*)d_in[8];
    const float* Wc   = (const float*)d_in[9];
    const float* ascv = (const float*)d_in[10];
    const float* adcv = (const float*)d_in[11];
    const float* bc   = (const float*)d_in[12];
    const float* Wl   = (const float*)d_in[13];
    const float* bl   = (const float*)d_in[14];
    const float* Wr   = (const float*)d_in[15];
    const float* br   = (const float*)d_in[16];
    float* out = (float*)d_out;

    char* w = (char*)d_ws;
    unsigned short* hpb = (unsigned short*)w; w += (size_t)NN*DIM*2;
    unsigned short* hcb = (unsigned short*)w; w += (size_t)NN*DIM*2;
    unsigned* Xbf = (unsigned*)w; w += (size_t)NN*(DIM/2)*4;
    unsigned short* WT4 = (unsigned short*)w; w += (size_t)4*DIM*DIM*2;
    float* wa  = (float*)w; w += (size_t)4*DIM*4;
    float* asp = (float*)w; w += (size_t)NN*4;
    float* adp = (float*)w; w += (size_t)NN*4;
    float* asc = (float*)w; w += (size_t)NN*4;
    float* adc = (float*)w; w += (size_t)NN*4;
    int* n2s  = (int*)w; w += (size_t)NN*4;
    unsigned* bm = (unsigned*)w; w += (size_t)((NBM+3)&~3)*4;
    int* cnt  = (int*)w; w += (size_t)NSEG*4;
    int* csr  = (int*)w; w += (size_t)NSEG*SEGCAP*4;
    float* bufP = (float*)w; w += (size_t)NT*NSLOT*DIM*4;
    float* bufC = (float*)w; w += (size_t)NT*NSLOT*DIM*4;
    unsigned* meanb = (unsigned*)w; w += (size_t)NT*NSLOT*(DIM/2)*4;
    float* mWl = (float*)w; w += (size_t)NT*NSLOT*DIM*4;
    float* xWr = (float*)w; w += (size_t)NSLOT*DIM*4;

    hipMemsetAsync(n2s, 0x7F, (size_t)NN*4, stream);
    hipMemsetAsync(cnt, 0, (size_t)NSEG*4, stream);
    hipMemsetAsync(bm, 0, (size_t)NBM*4, stream);
    k_prep   <<<5, 256, 0, stream>>>(Wp, Wc, Wl, Wr, aspv, adpv, ascv, adcv,
                                     s, n2s, bm, wa, WT4);
    k_cast   <<<(NN+3)/4, 256, 0, stream>>>(X, wa, Xbf, asp, adp, asc, adc);
    k_gemm   <<<(NN+63)/64, 256, 0, stream>>>((const unsigned short*)Xbf, WT4, hpb, hcb);
    k_build  <<<dim3(118, 18), 256, 0, stream>>>(EI, bm, n2s, cnt, csr);
    k_aggr   <<<NSEG/4, 256, 0, stream>>>((const unsigned*)hpb, (const unsigned*)hcb, Xbf,
                                          asp, adp, asc, adc, bp, bc, s, cnt, csr,
                                          bufP, bufC, meanb);
    k_sgemm  <<<112, 256, 0, stream>>>((const unsigned short*)meanb, Xbf, WT4, s, mWl, xWr);
    k_gather <<<NT*NSLOT*DIM/256, 256, 0, stream>>>(s, n2s, bufP, bufC, mWl, xWr, bl, br, out);
}

// Round 7
// 139.205 us; speedup vs baseline: 1.1062x; 1.1062x over previous
//
#include <hip/hip_runtime.h>
#include <hip/hip_bf16.h>

#define NN 30000
#define DIM 128
#define NT 6
#define NE 480000
#define NSLOT 1024
#define NSEG (NT*3*NSLOT)   // 18432
#define SEGCAP 96
#define NBM ((NN+31)/32)    // 938
#define QCAP 2048

typedef __attribute__((ext_vector_type(8))) short bf16x8;
typedef __attribute__((ext_vector_type(4))) float f32x4;

__device__ __forceinline__ float lrelu(float x){ return x > 0.f ? x : 0.2f*x; }
__device__ __forceinline__ unsigned short f2b(float f){
    unsigned u = __float_as_uint(f);
    u = (u + 0x7FFFu + ((u>>16)&1u)) >> 16;
    return (unsigned short)u;
}
__device__ __forceinline__ float b2f(unsigned short b){
    return __uint_as_float(((unsigned)b)<<16);
}

// blocks 0..3 -> Wp,Wc,Wl,Wr transposed bf16 (+wa for 0,1); block 4 -> slotmap
__global__ void k_prep(const float* __restrict__ Wp, const float* __restrict__ Wc,
        const float* __restrict__ Wl, const float* __restrict__ Wr,
        const float* __restrict__ aspv, const float* __restrict__ adpv,
        const float* __restrict__ ascv, const float* __restrict__ adcv,
        const int* __restrict__ s, int* __restrict__ n2s, unsigned* __restrict__ bm,
        float* __restrict__ wa, unsigned short* __restrict__ WT4){
    int m = blockIdx.x, t = threadIdx.x;
    if (m == 4){
        for (int i = t; i < NSLOT; i += 256){
            int v = s[i];
            atomicMin(&n2s[v], i);
            atomicOr(&bm[v>>5], 1u << (v&31));
        }
        return;
    }
    const float* W = (m==0) ? Wp : (m==1) ? Wc : (m==2) ? Wl : Wr;
    unsigned short* WT = WT4 + (size_t)m*DIM*DIM;
    if (m < 2 && t < DIM){
        const float* avs = m ? ascv : aspv;
        const float* avd = m ? adcv : adpv;
        float* wab = wa + m*2*DIM;
        float sv = 0.f, dv = 0.f;
        for (int n = 0; n < DIM; n++){
            float w = W[t*DIM + n];
            sv += w*avs[n]; dv += w*avd[n];
        }
        wab[t] = sv; wab[DIM + t] = dv;
    }
    for (int j = t; j < DIM*DIM; j += blockDim.x){
        int n = j >> 7, k = j & 127;
        WT[n*DIM + k] = f2b(W[k*DIM + n]);
    }
}

// wave per node: cast X row to bf16 + 4 attention scalars (f32 via wa)
__global__ __launch_bounds__(256) void k_cast(const float* __restrict__ X,
        const float* __restrict__ wa, unsigned* __restrict__ Xbf,
        float* __restrict__ asp, float* __restrict__ adp,
        float* __restrict__ asc, float* __restrict__ adc){
    int gw = (blockIdx.x*blockDim.x + threadIdx.x) >> 6;
    int lane = threadIdx.x & 63;
    if (gw >= NN) return;
    float2 x = *(const float2*)&X[(size_t)gw*DIM + lane*2];
    Xbf[(size_t)gw*(DIM/2) + lane] = (unsigned)f2b(x.x) | ((unsigned)f2b(x.y) << 16);
    float sp = x.x*wa[2*lane]     + x.y*wa[2*lane+1];
    float dp = x.x*wa[128+2*lane] + x.y*wa[128+2*lane+1];
    float sc = x.x*wa[256+2*lane] + x.y*wa[256+2*lane+1];
    float dc = x.x*wa[384+2*lane] + x.y*wa[384+2*lane+1];
    #pragma unroll
    for (int off = 32; off; off >>= 1){
        sp += __shfl_xor(sp, off); dp += __shfl_xor(dp, off);
        sc += __shfl_xor(sc, off); dc += __shfl_xor(dc, off);
    }
    if (lane == 0){ asp[gw] = sp; adp[gw] = dp; asc[gw] = sc; adc[gw] = dc; }
}

// MFMA GEMM: wave = 16 rows x 128 cols, both P and C matrices; bf16 out.
__global__ __launch_bounds__(256) void k_gemm(const unsigned short* __restrict__ Xbf,
        const unsigned short* __restrict__ WT4,
        unsigned short* __restrict__ hpb, unsigned short* __restrict__ hcb){
    const unsigned short* WTp = WT4;
    const unsigned short* WTc = WT4 + DIM*DIM;
    int wid = threadIdx.x >> 6, lane = threadIdx.x & 63;
    int r0 = blockIdx.x*64 + wid*16;
    int arow = r0 + (lane & 15); if (arow > NN-1) arow = NN-1;
    int g = lane >> 4;
    bf16x8 A[4];
    #pragma unroll
    for (int ks = 0; ks < 4; ks++)
        A[ks] = *(const bf16x8*)&Xbf[(size_t)arow*DIM + ks*32 + g*8];
    int cl = lane & 15;
    #pragma unroll
    for (int ct = 0; ct < 8; ct++){
        f32x4 aP = {0.f,0.f,0.f,0.f}, aC = {0.f,0.f,0.f,0.f};
        int bcol = ct*16 + cl;
        #pragma unroll
        for (int ks = 0; ks < 4; ks++){
            bf16x8 bP = *(const bf16x8*)&WTp[bcol*DIM + ks*32 + g*8];
            bf16x8 bC = *(const bf16x8*)&WTc[bcol*DIM + ks*32 + g*8];
            aP = __builtin_amdgcn_mfma_f32_16x16x32_bf16(A[ks], bP, aP, 0, 0, 0);
            aC = __builtin_amdgcn_mfma_f32_16x16x32_bf16(A[ks], bC, aC, 0, 0, 0);
        }
        #pragma unroll
        for (int r = 0; r < 4; r++){
            int row = r0 + g*4 + r;
            if (row < NN){
                hpb[(size_t)row*DIM + bcol] = f2b(aP[r]);
                hcb[(size_t)row*DIM + bcol] = f2b(aC[r]);
            }
        }
    }
}

// CSR build, two-phase: (1) stream + LDS-queue matches, (2) parallel drain
__global__ __launch_bounds__(256) void k_build(const int* __restrict__ EI,
        const unsigned* __restrict__ bm, const int* __restrict__ n2s,
        int* __restrict__ cnt, int* __restrict__ csr){
    __shared__ unsigned bms[NBM];
    __shared__ unsigned q[QCAP];
    __shared__ int qn;
    for (int j = threadIdx.x; j < NBM; j += 256) bms[j] = bm[j];
    if (threadIdx.x == 0) qn = 0;
    __syncthreads();
    const int Q = NE/4;                  // 120000 int4 per row
    const int G = gridDim.x*blockDim.x;  // threads per row
    int row = blockIdx.y;
    const int4* dstp = (const int4*)(EI + (size_t)(2*row+1)*NE);
    const int4* srcp = (const int4*)(EI + (size_t)(2*row)*NE);
    int tid = blockIdx.x*blockDim.x + threadIdx.x;
    #pragma unroll
    for (int u = 0; u < 4; u++){
        int ix = tid + u*G;
        if (ix < Q){
            int4 d = dstp[ix];
            unsigned m0 = (bms[d.x>>5] >> (d.x&31)) & 1u;
            unsigned m1 = (bms[d.y>>5] >> (d.y&31)) & 1u;
            unsigned m2 = (bms[d.z>>5] >> (d.z&31)) & 1u;
            unsigned m3 = (bms[d.w>>5] >> (d.w&31)) & 1u;
            if (m0|m1|m2|m3){
                int4 sv = srcp[ix];
                if (m0){ int p = atomicAdd(&qn,1); if (p < QCAP) q[p] = ((unsigned)d.x<<15) | (unsigned)sv.x; }
                if (m1){ int p = atomicAdd(&qn,1); if (p < QCAP) q[p] = ((unsigned)d.y<<15) | (unsigned)sv.y; }
                if (m2){ int p = atomicAdd(&qn,1); if (p < QCAP) q[p] = ((unsigned)d.z<<15) | (unsigned)sv.z; }
                if (m3){ int p = atomicAdd(&qn,1); if (p < QCAP) q[p] = ((unsigned)d.w<<15) | (unsigned)sv.w; }
            }
        }
    }
    __syncthreads();
    int base = row*NSLOT;
    int tot = qn; if (tot > QCAP) tot = QCAP;
    for (int j = threadIdx.x; j < tot; j += 256){
        unsigned e = q[j];
        int dst = (int)(e >> 15);
        int src = (int)(e & 32767u);
        int sl = n2s[dst];
        int p = atomicAdd(&cnt[base+sl], 1);
        if (p < SEGCAP) csr[(size_t)(base+sl)*SEGCAP + p] = src;
    }
}

// wave per segment: g<2 -> GAT (p/c), g==2 -> SAGE neighbor-mean
__global__ __launch_bounds__(256) void k_aggr(
        const unsigned* __restrict__ hpb, const unsigned* __restrict__ hcb,
        const unsigned* __restrict__ Xbf,
        const float* __restrict__ asp, const float* __restrict__ adp,
        const float* __restrict__ asc, const float* __restrict__ adc,
        const float* __restrict__ bp, const float* __restrict__ bc,
        const int* __restrict__ s, const int* __restrict__ cnt, const int* __restrict__ csr,
        float* __restrict__ bufP, float* __restrict__ bufC, unsigned* __restrict__ meanb){
    int gw = (blockIdx.x*blockDim.x + threadIdx.x) >> 6;
    int lane = threadIdx.x & 63;
    if (gw >= NSEG) return;
    int slot = gw & (NSLOT-1);
    int tg = gw >> 10;
    int g = tg % 3, t = tg / 3;
    int n = cnt[gw]; if (n > SEGCAP) n = SEGCAP;
    const int* lst = csr + (size_t)gw*SEGCAP;
    if (g == 2){
        float m0 = 0.f, m1 = 0.f;
        for (int j = 0; j < n; j++){
            unsigned pk = Xbf[(size_t)lst[j]*(DIM/2) + lane];
            m0 += b2f((unsigned short)(pk & 0xFFFF));
            m1 += b2f((unsigned short)(pk >> 16));
        }
        float c = (float)n; if (c < 1.f) c = 1.f;
        float invc = 1.f/c;
        meanb[(size_t)(t*NSLOT+slot)*(DIM/2) + lane] =
            (unsigned)f2b(m0*invc) | ((unsigned)f2b(m1*invc) << 16);
        return;
    }
    const unsigned* h = g ? hcb : hpb;
    const float* as = g ? asc : asp;
    const float* ad = g ? adc : adp;
    const float* b  = g ? bc  : bp;
    int v = s[slot];
    float adv = ad[v];
    float eself = lrelu(as[v] + adv);
    float m = eself;
    for (int j = lane; j < n; j += 64)
        m = fmaxf(m, lrelu(as[lst[j]] + adv));
    #pragma unroll
    for (int off = 32; off; off >>= 1) m = fmaxf(m, __shfl_xor(m, off));
    float pself = __expf(eself - m);
    float denom = pself;
    unsigned pkv = h[(size_t)v*(DIM/2) + lane];
    float a0 = pself * b2f((unsigned short)(pkv & 0xFFFF));
    float a1 = pself * b2f((unsigned short)(pkv >> 16));
    for (int j = 0; j < n; j++){
        int src = lst[j];
        float p = __expf(lrelu(as[src] + adv) - m);
        denom += p;
        unsigned pk = h[(size_t)src*(DIM/2) + lane];
        a0 += p * b2f((unsigned short)(pk & 0xFFFF));
        a1 += p * b2f((unsigned short)(pk >> 16));
    }
    float inv = 1.f/denom;
    float* ob = g ? bufC : bufP;
    ob[(size_t)(t*NSLOT+slot)*DIM + 2*lane]   = a0*inv + b[2*lane];
    ob[(size_t)(t*NSLOT+slot)*DIM + 2*lane+1] = a1*inv + b[2*lane+1];
}

// blocks 0..95: meanb@WlT -> mWl; blocks 96..111: Xbf[s[slot]]@WrT -> xWr
__global__ __launch_bounds__(256) void k_sgemm(const unsigned short* __restrict__ meanb,
        const unsigned* __restrict__ Xbf, const unsigned short* __restrict__ WT4,
        const int* __restrict__ s,
        float* __restrict__ mWl, float* __restrict__ xWr){
    int task = (blockIdx.x >= 96);
    int blk  = task ? (blockIdx.x - 96) : blockIdx.x;
    const unsigned short* WT = WT4 + (size_t)(task ? 3 : 2)*DIM*DIM;
    float* out = task ? xWr : mWl;
    int rows = task ? NSLOT : NT*NSLOT;
    int wid = threadIdx.x >> 6, lane = threadIdx.x & 63;
    int r0 = blk*64 + wid*16;
    int ar = r0 + (lane & 15); if (ar > rows-1) ar = rows-1;
    int g = lane >> 4;
    const unsigned short* Arow = task
        ? (const unsigned short*)(Xbf + (size_t)s[ar]*(DIM/2))
        : (meanb + (size_t)ar*DIM);
    bf16x8 Af[4];
    #pragma unroll
    for (int ks = 0; ks < 4; ks++)
        Af[ks] = *(const bf16x8*)&Arow[ks*32 + g*8];
    int cl = lane & 15;
    #pragma unroll
    for (int ct = 0; ct < 8; ct++){
        f32x4 acc = {0.f,0.f,0.f,0.f};
        int bcol = ct*16 + cl;
        #pragma unroll
        for (int ks = 0; ks < 4; ks++){
            bf16x8 bF = *(const bf16x8*)&WT[bcol*DIM + ks*32 + g*8];
            acc = __builtin_amdgcn_mfma_f32_16x16x32_bf16(Af[ks], bF, acc, 0, 0, 0);
        }
        #pragma unroll
        for (int r = 0; r < 4; r++){
            int row = r0 + g*4 + r;
            if (row < rows) out[(size_t)row*DIM + bcol] = acc[r];
        }
    }
}

__global__ void k_gather(const int* __restrict__ s, const int* __restrict__ n2s,
                         const float* __restrict__ bufP, const float* __restrict__ bufC,
                         const float* __restrict__ mWl, const float* __restrict__ xWr,
                         const float* __restrict__ bl, const float* __restrict__ br,
                         float* __restrict__ out){
    int i = blockIdx.x*blockDim.x + threadIdx.x;
    if (i >= NT*NSLOT*DIM) return;
    int d = i & 127;
    int r = (i >> 7) & (NSLOT-1);
    int t = i >> 17;
    int rep = n2s[s[r]];
    size_t j = (size_t)(t*NSLOT + rep)*DIM + d;
    out[i] = (bufP[j] + bufC[j] + mWl[j] + xWr[(size_t)rep*DIM + d] + bl[d] + br[d]) * (1.f/3.f);
}

extern "C" void kernel_launch(void* const* d_in, const int* in_sizes, int n_in,
                              void* d_out, int out_size, void* d_ws, size_t ws_size,
                              hipStream_t stream) {
    const int*   s    = (const int*)d_in[0];
    const int*   EI   = (const int*)d_in[3];
    const float* X    = (const float*)d_in[4];
    const float* Wp   = (const float*)d_in[5];
    const float* aspv = (const float*)d_in[6];
    const float* adpv = (const float*)d_in[7];
    const float* bp   = (const float*)d_in[8];
    const float* Wc   = (const float*)d_in[9];
    const float* ascv = (const float*)d_in[10];
    const float* adcv = (const float*)d_in[11];
    const float* bc   = (const float*)d_in[12];
    const float* Wl   = (const float*)d_in[13];
    const float* bl   = (const float*)d_in[14];
    const float* Wr   = (const float*)d_in[15];
    const float* br   = (const float*)d_in[16];
    float* out = (float*)d_out;

    char* w = (char*)d_ws;
    unsigned short* hpb = (unsigned short*)w; w += (size_t)NN*DIM*2;
    unsigned short* hcb = (unsigned short*)w; w += (size_t)NN*DIM*2;
    unsigned* Xbf = (unsigned*)w; w += (size_t)NN*(DIM/2)*4;
    unsigned short* WT4 = (unsigned short*)w; w += (size_t)4*DIM*DIM*2;
    float* wa  = (float*)w; w += (size_t)4*DIM*4;
    float* asp = (float*)w; w += (size_t)NN*4;
    float* adp = (float*)w; w += (size_t)NN*4;
    float* asc = (float*)w; w += (size_t)NN*4;
    float* adc = (float*)w; w += (size_t)NN*4;
    int* n2s  = (int*)w; w += (size_t)NN*4;
    unsigned* bm = (unsigned*)w; w += (size_t)((NBM+3)&~3)*4;
    int* cnt  = (int*)w; w += (size_t)NSEG*4;
    int* csr  = (int*)w; w += (size_t)NSEG*SEGCAP*4;
    float* bufP = (float*)w; w += (size_t)NT*NSLOT*DIM*4;
    float* bufC = (float*)w; w += (size_t)NT*NSLOT*DIM*4;
    unsigned* meanb = (unsigned*)w; w += (size_t)NT*NSLOT*(DIM/2)*4;
    float* mWl = (float*)w; w += (size_t)NT*NSLOT*DIM*4;
    float* xWr = (float*)w; w += (size_t)NSLOT*DIM*4;

    hipMemsetAsync(n2s, 0x7F, (size_t)NN*4, stream);
    hipMemsetAsync(cnt, 0, (size_t)NSEG*4, stream);
    hipMemsetAsync(bm, 0, (size_t)NBM*4, stream);
    k_prep   <<<5, 256, 0, stream>>>(Wp, Wc, Wl, Wr, aspv, adpv, ascv, adcv,
                                     s, n2s, bm, wa, WT4);
    k_cast   <<<(NN+3)/4, 256, 0, stream>>>(X, wa, Xbf, asp, adp, asc, adc);
    k_gemm   <<<(NN+63)/64, 256, 0, stream>>>((const unsigned short*)Xbf, WT4, hpb, hcb);
    k_build  <<<dim3(118, 18), 256, 0, stream>>>(EI, bm, n2s, cnt, csr);
    k_aggr   <<<NSEG/4, 256, 0, stream>>>((const unsigned*)hpb, (const unsigned*)hcb, Xbf,
                                          asp, adp, asc, adc, bp, bc, s, cnt, csr,
                                          bufP, bufC, meanb);
    k_sgemm  <<<112, 256, 0, stream>>>((const unsigned short*)meanb, Xbf, WT4, s, mWl, xWr);
    k_gather <<<NT*NSLOT*DIM/256, 256, 0, stream>>>(s, n2s, bufP, bufC, mWl, xWr, bl, br, out);
}

// Round 8
// 106.085 us; speedup vs baseline: 1.4516x; 1.3122x over previous
//
#include <hip/hip_runtime.h>
#include <hip/hip_bf16.h>

#define NN 30000
#define DIM 128
#define NT 6
#define NE 480000
#define NSLOT 1024
#define NSEG (NT*3*NSLOT)   // 18432
#define SEGCAP 96
#define NBM ((NN+31)/32)    // 938
#define QCAP 2048

typedef __attribute__((ext_vector_type(8))) short bf16x8;
typedef __attribute__((ext_vector_type(4))) float f32x4;

__device__ __forceinline__ float lrelu(float x){ return x > 0.f ? x : 0.2f*x; }
__device__ __forceinline__ unsigned short f2b(float f){
    unsigned u = __float_as_uint(f);
    u = (u + 0x7FFFu + ((u>>16)&1u)) >> 16;
    return (unsigned short)u;
}
__device__ __forceinline__ float b2f(unsigned short b){
    return __uint_as_float(((unsigned)b)<<16);
}
__device__ __forceinline__ float blo(unsigned p){ return b2f((unsigned short)(p & 0xFFFF)); }
__device__ __forceinline__ float bhi(unsigned p){ return b2f((unsigned short)(p >> 16)); }

// blocks 0..3 -> Wp,Wc,Wl,Wr transposed bf16 (+wa for 0,1); block 4 -> slotmap
__global__ void k_prep(const float* __restrict__ Wp, const float* __restrict__ Wc,
        const float* __restrict__ Wl, const float* __restrict__ Wr,
        const float* __restrict__ aspv, const float* __restrict__ adpv,
        const float* __restrict__ ascv, const float* __restrict__ adcv,
        const int* __restrict__ s, int* __restrict__ n2s, unsigned* __restrict__ bm,
        float* __restrict__ wa, unsigned short* __restrict__ WT4){
    int m = blockIdx.x, t = threadIdx.x;
    if (m == 4){
        for (int i = t; i < NSLOT; i += 256){
            int v = s[i];
            atomicMin(&n2s[v], i);
            atomicOr(&bm[v>>5], 1u << (v&31));
        }
        return;
    }
    const float* W = (m==0) ? Wp : (m==1) ? Wc : (m==2) ? Wl : Wr;
    unsigned short* WT = WT4 + (size_t)m*DIM*DIM;
    if (m < 2 && t < DIM){
        const float* avs = m ? ascv : aspv;
        const float* avd = m ? adcv : adpv;
        float* wab = wa + m*2*DIM;
        float sv = 0.f, dv = 0.f;
        for (int n = 0; n < DIM; n++){
            float w = W[t*DIM + n];
            sv += w*avs[n]; dv += w*avd[n];
        }
        wab[t] = sv; wab[DIM + t] = dv;
    }
    for (int j = t; j < DIM*DIM; j += blockDim.x){
        int n = j >> 7, k = j & 127;
        WT[n*DIM + k] = f2b(W[k*DIM + n]);
    }
}

// fused: X f32 -> Xbf + att scalars (f32) + double MFMA GEMM -> hpb/hcb (bf16)
__global__ __launch_bounds__(256) void k_xform(const float* __restrict__ X,
        const unsigned short* __restrict__ WT4, const float* __restrict__ wa,
        unsigned* __restrict__ Xbf,
        unsigned short* __restrict__ hpb, unsigned short* __restrict__ hcb,
        float* __restrict__ asp, float* __restrict__ adp,
        float* __restrict__ asc, float* __restrict__ adc){
    const unsigned short* WTp = WT4;
    const unsigned short* WTc = WT4 + DIM*DIM;
    int wid = threadIdx.x >> 6, lane = threadIdx.x & 63;
    int r0 = blockIdx.x*64 + wid*16;
    int arow = r0 + (lane & 15);
    bool rv = arow < NN;
    int ar = rv ? arow : NN-1;
    int g = lane >> 4;
    float xf[4][8];
    bf16x8 A[4];
    #pragma unroll
    for (int ks = 0; ks < 4; ks++){
        const float* px = &X[(size_t)ar*DIM + ks*32 + g*8];
        float4 u0 = *(const float4*)px;
        float4 u1 = *(const float4*)(px+4);
        xf[ks][0]=u0.x; xf[ks][1]=u0.y; xf[ks][2]=u0.z; xf[ks][3]=u0.w;
        xf[ks][4]=u1.x; xf[ks][5]=u1.y; xf[ks][6]=u1.z; xf[ks][7]=u1.w;
        bf16x8 a;
        #pragma unroll
        for (int i = 0; i < 8; i++) a[i] = (short)f2b(xf[ks][i]);
        A[ks] = a;
        unsigned* xb = &Xbf[(size_t)ar*64 + (ks*32 + g*8)/2];
        #pragma unroll
        for (int i = 0; i < 4; i++)
            xb[i] = (unsigned)(unsigned short)a[2*i] | ((unsigned)(unsigned short)a[2*i+1] << 16);
    }
    // attention dots in f32
    float sp=0.f, dp=0.f, sc=0.f, dc=0.f;
    #pragma unroll
    for (int ks = 0; ks < 4; ks++){
        int kb = ks*32 + g*8;
        #pragma unroll
        for (int i = 0; i < 8; i++){
            float xv = xf[ks][i];
            sp += xv*wa[kb+i];
            dp += xv*wa[128+kb+i];
            sc += xv*wa[256+kb+i];
            dc += xv*wa[384+kb+i];
        }
    }
    sp += __shfl_xor(sp,16); sp += __shfl_xor(sp,32);
    dp += __shfl_xor(dp,16); dp += __shfl_xor(dp,32);
    sc += __shfl_xor(sc,16); sc += __shfl_xor(sc,32);
    dc += __shfl_xor(dc,16); dc += __shfl_xor(dc,32);
    if (g == 0 && rv){ asp[arow]=sp; adp[arow]=dp; asc[arow]=sc; adc[arow]=dc; }
    // MFMA
    int cl = lane & 15;
    #pragma unroll
    for (int ct = 0; ct < 8; ct++){
        f32x4 aP = {0.f,0.f,0.f,0.f}, aC = {0.f,0.f,0.f,0.f};
        int bcol = ct*16 + cl;
        #pragma unroll
        for (int ks = 0; ks < 4; ks++){
            bf16x8 bP = *(const bf16x8*)&WTp[bcol*DIM + ks*32 + g*8];
            bf16x8 bC = *(const bf16x8*)&WTc[bcol*DIM + ks*32 + g*8];
            aP = __builtin_amdgcn_mfma_f32_16x16x32_bf16(A[ks], bP, aP, 0, 0, 0);
            aC = __builtin_amdgcn_mfma_f32_16x16x32_bf16(A[ks], bC, aC, 0, 0, 0);
        }
        #pragma unroll
        for (int r = 0; r < 4; r++){
            int row = r0 + g*4 + r;
            if (row < NN){
                hpb[(size_t)row*DIM + bcol] = f2b(aP[r]);
                hcb[(size_t)row*DIM + bcol] = f2b(aC[r]);
            }
        }
    }
}

// CSR build, two-phase: (1) stream + LDS-queue matches, (2) parallel drain
__global__ __launch_bounds__(256) void k_build(const int* __restrict__ EI,
        const unsigned* __restrict__ bm, const int* __restrict__ n2s,
        int* __restrict__ cnt, int* __restrict__ csr){
    __shared__ unsigned bms[NBM];
    __shared__ unsigned q[QCAP];
    __shared__ int qn;
    for (int j = threadIdx.x; j < NBM; j += 256) bms[j] = bm[j];
    if (threadIdx.x == 0) qn = 0;
    __syncthreads();
    const int Q = NE/4;
    const int G = gridDim.x*blockDim.x;
    int row = blockIdx.y;
    const int4* dstp = (const int4*)(EI + (size_t)(2*row+1)*NE);
    const int4* srcp = (const int4*)(EI + (size_t)(2*row)*NE);
    int tid = blockIdx.x*blockDim.x + threadIdx.x;
    #pragma unroll
    for (int u = 0; u < 4; u++){
        int ix = tid + u*G;
        if (ix < Q){
            int4 d = dstp[ix];
            unsigned m0 = (bms[d.x>>5] >> (d.x&31)) & 1u;
            unsigned m1 = (bms[d.y>>5] >> (d.y&31)) & 1u;
            unsigned m2 = (bms[d.z>>5] >> (d.z&31)) & 1u;
            unsigned m3 = (bms[d.w>>5] >> (d.w&31)) & 1u;
            if (m0|m1|m2|m3){
                int4 sv = srcp[ix];
                if (m0){ int p = atomicAdd(&qn,1); if (p < QCAP) q[p] = ((unsigned)d.x<<15) | (unsigned)sv.x; }
                if (m1){ int p = atomicAdd(&qn,1); if (p < QCAP) q[p] = ((unsigned)d.y<<15) | (unsigned)sv.y; }
                if (m2){ int p = atomicAdd(&qn,1); if (p < QCAP) q[p] = ((unsigned)d.z<<15) | (unsigned)sv.z; }
                if (m3){ int p = atomicAdd(&qn,1); if (p < QCAP) q[p] = ((unsigned)d.w<<15) | (unsigned)sv.w; }
            }
        }
    }
    __syncthreads();
    int base = row*NSLOT;
    int tot = qn; if (tot > QCAP) tot = QCAP;
    for (int j = threadIdx.x; j < tot; j += 256){
        unsigned e = q[j];
        int dst = (int)(e >> 15);
        int src = (int)(e & 32767u);
        int sl = n2s[dst];
        int p = atomicAdd(&cnt[base+sl], 1);
        if (p < SEGCAP) csr[(size_t)(base+sl)*SEGCAP + p] = src;
    }
}

// wave per segment; lane-parallel logits, unroll-4 row gathers
__global__ __launch_bounds__(256) void k_aggr(
        const unsigned* __restrict__ hpb, const unsigned* __restrict__ hcb,
        const unsigned* __restrict__ Xbf,
        const float* __restrict__ asp, const float* __restrict__ adp,
        const float* __restrict__ asc, const float* __restrict__ adc,
        const float* __restrict__ bp, const float* __restrict__ bc,
        const int* __restrict__ s, const int* __restrict__ cnt, const int* __restrict__ csr,
        float* __restrict__ bufP, float* __restrict__ bufC, unsigned* __restrict__ meanb){
    int gw = (blockIdx.x*blockDim.x + threadIdx.x) >> 6;
    int lane = threadIdx.x & 63;
    if (gw >= NSEG) return;
    int slot = gw & (NSLOT-1);
    int tg = gw >> 10;
    int g = tg % 3, t = tg / 3;
    int n = cnt[gw]; if (n > SEGCAP) n = SEGCAP;
    const int* lst = csr + (size_t)gw*SEGCAP;
    int src0 = (lane < n) ? lst[lane] : 0;
    int src1 = (64+lane < n) ? lst[64+lane] : 0;
    int n0 = n < 64 ? n : 64;

    if (g == 2){
        float m0 = 0.f, m1 = 0.f;
        int j = 0;
        for (; j+3 < n0; j += 4){
            int s0=__shfl(src0,j), s1=__shfl(src0,j+1), s2=__shfl(src0,j+2), s3=__shfl(src0,j+3);
            unsigned k0=Xbf[(size_t)s0*64+lane];
            unsigned k1=Xbf[(size_t)s1*64+lane];
            unsigned k2=Xbf[(size_t)s2*64+lane];
            unsigned k3=Xbf[(size_t)s3*64+lane];
            m0 += blo(k0)+blo(k1)+blo(k2)+blo(k3);
            m1 += bhi(k0)+bhi(k1)+bhi(k2)+bhi(k3);
        }
        for (; j < n0; j++){
            int sj=__shfl(src0,j);
            unsigned pk=Xbf[(size_t)sj*64+lane];
            m0 += blo(pk); m1 += bhi(pk);
        }
        for (j = 64; j < n; j++){
            int sj=__shfl(src1,j-64);
            unsigned pk=Xbf[(size_t)sj*64+lane];
            m0 += blo(pk); m1 += bhi(pk);
        }
        float c = n ? (float)n : 1.f;
        float invc = 1.f/c;
        meanb[(size_t)(t*NSLOT+slot)*64 + lane] =
            (unsigned)f2b(m0*invc) | ((unsigned)f2b(m1*invc) << 16);
        return;
    }
    const unsigned* h = g ? hcb : hpb;
    const float* as = g ? asc : asp;
    const float* ad = g ? adc : adp;
    const float* b  = g ? bc  : bp;
    int v = s[slot];
    float adv = ad[v];
    float eself = lrelu(as[v] + adv);
    float e0 = (lane < n)    ? lrelu(as[src0]+adv) : -3e38f;
    float e1 = (64+lane < n) ? lrelu(as[src1]+adv) : -3e38f;
    float m = fmaxf(eself, fmaxf(e0, e1));
    #pragma unroll
    for (int off = 32; off; off >>= 1) m = fmaxf(m, __shfl_xor(m, off));
    float pv0 = (lane < n)    ? __expf(e0 - m) : 0.f;
    float pv1 = (64+lane < n) ? __expf(e1 - m) : 0.f;
    float ds = pv0 + pv1;
    #pragma unroll
    for (int off = 32; off; off >>= 1) ds += __shfl_xor(ds, off);
    float pself = __expf(eself - m);
    float denom = pself + ds;
    unsigned pkv = h[(size_t)v*64 + lane];
    float a0 = pself * blo(pkv);
    float a1 = pself * bhi(pkv);
    int j = 0;
    for (; j+3 < n0; j += 4){
        int s0=__shfl(src0,j), s1=__shfl(src0,j+1), s2=__shfl(src0,j+2), s3=__shfl(src0,j+3);
        float q0=__shfl(pv0,j), q1=__shfl(pv0,j+1), q2=__shfl(pv0,j+2), q3=__shfl(pv0,j+3);
        unsigned k0=h[(size_t)s0*64+lane];
        unsigned k1=h[(size_t)s1*64+lane];
        unsigned k2=h[(size_t)s2*64+lane];
        unsigned k3=h[(size_t)s3*64+lane];
        a0 += q0*blo(k0) + q1*blo(k1) + q2*blo(k2) + q3*blo(k3);
        a1 += q0*bhi(k0) + q1*bhi(k1) + q2*bhi(k2) + q3*bhi(k3);
    }
    for (; j < n0; j++){
        int sj=__shfl(src0,j);
        float qj=__shfl(pv0,j);
        unsigned pk=h[(size_t)sj*64+lane];
        a0 += qj*blo(pk); a1 += qj*bhi(pk);
    }
    for (j = 64; j < n; j++){
        int sj=__shfl(src1,j-64);
        float qj=__shfl(pv1,j-64);
        unsigned pk=h[(size_t)sj*64+lane];
        a0 += qj*blo(pk); a1 += qj*bhi(pk);
    }
    float inv = 1.f/denom;
    float* ob = g ? bufC : bufP;
    ob[(size_t)(t*NSLOT+slot)*DIM + 2*lane]   = a0*inv + b[2*lane];
    ob[(size_t)(t*NSLOT+slot)*DIM + 2*lane+1] = a1*inv + b[2*lane+1];
}

// blocks 0..95: meanb@WlT -> mWl; blocks 96..111: Xbf[s[slot]]@WrT -> xWr
__global__ __launch_bounds__(256) void k_sgemm(const unsigned short* __restrict__ meanb,
        const unsigned* __restrict__ Xbf, const unsigned short* __restrict__ WT4,
        const int* __restrict__ s,
        float* __restrict__ mWl, float* __restrict__ xWr){
    int task = (blockIdx.x >= 96);
    int blk  = task ? (blockIdx.x - 96) : blockIdx.x;
    const unsigned short* WT = WT4 + (size_t)(task ? 3 : 2)*DIM*DIM;
    float* out = task ? xWr : mWl;
    int rows = task ? NSLOT : NT*NSLOT;
    int wid = threadIdx.x >> 6, lane = threadIdx.x & 63;
    int r0 = blk*64 + wid*16;
    int ar = r0 + (lane & 15); if (ar > rows-1) ar = rows-1;
    int g = lane >> 4;
    const unsigned short* Arow = task
        ? (const unsigned short*)(Xbf + (size_t)s[ar]*64)
        : (meanb + (size_t)ar*DIM);
    bf16x8 Af[4];
    #pragma unroll
    for (int ks = 0; ks < 4; ks++)
        Af[ks] = *(const bf16x8*)&Arow[ks*32 + g*8];
    int cl = lane & 15;
    #pragma unroll
    for (int ct = 0; ct < 8; ct++){
        f32x4 acc = {0.f,0.f,0.f,0.f};
        int bcol = ct*16 + cl;
        #pragma unroll
        for (int ks = 0; ks < 4; ks++){
            bf16x8 bF = *(const bf16x8*)&WT[bcol*DIM + ks*32 + g*8];
            acc = __builtin_amdgcn_mfma_f32_16x16x32_bf16(Af[ks], bF, acc, 0, 0, 0);
        }
        #pragma unroll
        for (int r = 0; r < 4; r++){
            int row = r0 + g*4 + r;
            if (row < rows) out[(size_t)row*DIM + bcol] = acc[r];
        }
    }
}

__global__ void k_gather(const int* __restrict__ s, const int* __restrict__ n2s,
                         const float* __restrict__ bufP, const float* __restrict__ bufC,
                         const float* __restrict__ mWl, const float* __restrict__ xWr,
                         const float* __restrict__ bl, const float* __restrict__ br,
                         float* __restrict__ out){
    int i = blockIdx.x*blockDim.x + threadIdx.x;
    if (i >= NT*NSLOT*DIM) return;
    int d = i & 127;
    int r = (i >> 7) & (NSLOT-1);
    int t = i >> 17;
    int rep = n2s[s[r]];
    size_t j = (size_t)(t*NSLOT + rep)*DIM + d;
    out[i] = (bufP[j] + bufC[j] + mWl[j] + xWr[(size_t)rep*DIM + d] + bl[d] + br[d]) * (1.f/3.f);
}

extern "C" void kernel_launch(void* const* d_in, const int* in_sizes, int n_in,
                              void* d_out, int out_size, void* d_ws, size_t ws_size,
                              hipStream_t stream) {
    const int*   s    = (const int*)d_in[0];
    const int*   EI   = (const int*)d_in[3];
    const float* X    = (const float*)d_in[4];
    const float* Wp   = (const float*)d_in[5];
    const float* aspv = (const float*)d_in[6];
    const float* adpv = (const float*)d_in[7];
    const float* bp   = (const float*)d_in[8];
    const float* Wc   = (const float*)d_in[9];
    const float* ascv = (const float*)d_in[10];
    const float* adcv = (const float*)d_in[11];
    const float* bc   = (const float*)d_in[12];
    const float* Wl   = (const float*)d_in[13];
    const float* bl   = (const float*)d_in[14];
    const float* Wr   = (const float*)d_in[15];
    const float* br   = (const float*)d_in[16];
    float* out = (float*)d_out;

    char* w = (char*)d_ws;
    unsigned short* hpb = (unsigned short*)w; w += (size_t)NN*DIM*2;
    unsigned short* hcb = (unsigned short*)w; w += (size_t)NN*DIM*2;
    unsigned* Xbf = (unsigned*)w; w += (size_t)NN*(DIM/2)*4;
    unsigned short* WT4 = (unsigned short*)w; w += (size_t)4*DIM*DIM*2;
    float* wa  = (float*)w; w += (size_t)4*DIM*4;
    float* asp = (float*)w; w += (size_t)NN*4;
    float* adp = (float*)w; w += (size_t)NN*4;
    float* asc = (float*)w; w += (size_t)NN*4;
    float* adc = (float*)w; w += (size_t)NN*4;
    int* n2s  = (int*)w; w += (size_t)NN*4;
    int* cnt  = (int*)w; w += (size_t)NSEG*4;
    unsigned* bm = (unsigned*)w; w += (size_t)((NBM+3)&~3)*4;
    int* csr  = (int*)w; w += (size_t)NSEG*SEGCAP*4;
    float* bufP = (float*)w; w += (size_t)NT*NSLOT*DIM*4;
    float* bufC = (float*)w; w += (size_t)NT*NSLOT*DIM*4;
    unsigned* meanb = (unsigned*)w; w += (size_t)NT*NSLOT*(DIM/2)*4;
    float* mWl = (float*)w; w += (size_t)NT*NSLOT*DIM*4;
    float* xWr = (float*)w; w += (size_t)NSLOT*DIM*4;

    hipMemsetAsync(n2s, 0x7F, (size_t)NN*4, stream);
    hipMemsetAsync(cnt, 0, (size_t)(NSEG + ((NBM+3)&~3))*4, stream);
    k_prep   <<<5, 256, 0, stream>>>(Wp, Wc, Wl, Wr, aspv, adpv, ascv, adcv,
                                     s, n2s, bm, wa, WT4);
    k_xform  <<<(NN+63)/64, 256, 0, stream>>>(X, WT4, wa, Xbf, hpb, hcb,
                                              asp, adp, asc, adc);
    k_build  <<<dim3(118, 18), 256, 0, stream>>>(EI, bm, n2s, cnt, csr);
    k_aggr   <<<NSEG/4, 256, 0, stream>>>((const unsigned*)hpb, (const unsigned*)hcb, Xbf,
                                          asp, adp, asc, adc, bp, bc, s, cnt, csr,
                                          bufP, bufC, meanb);
    k_sgemm  <<<112, 256, 0, stream>>>((const unsigned short*)meanb, Xbf, WT4, s, mWl, xWr);
    k_gather <<<NT*NSLOT*DIM/256, 256, 0, stream>>>(s, n2s, bufP, bufC, mWl, xWr, bl, br, out);
}

// Round 9
// 91.273 us; speedup vs baseline: 1.6872x; 1.1623x over previous
//
#include <hip/hip_runtime.h>
#include <hip/hip_bf16.h>

#define NN 30000
#define DIM 128
#define NT 6
#define NE 480000
#define NSLOT 1024
#define NSEG (NT*3*NSLOT)   // 18432
#define SEGCAP 96
#define NBM ((NN+31)/32)    // 938
#define QCAP 2048
#define HB 2048             // hash slots

typedef __attribute__((ext_vector_type(8))) short bf16x8;
typedef __attribute__((ext_vector_type(4))) float f32x4;

__device__ __forceinline__ float lrelu(float x){ return x > 0.f ? x : 0.2f*x; }
__device__ __forceinline__ unsigned short f2b(float f){
    unsigned u = __float_as_uint(f);
    u = (u + 0x7FFFu + ((u>>16)&1u)) >> 16;
    return (unsigned short)u;
}
__device__ __forceinline__ float b2f(unsigned short b){
    return __uint_as_float(((unsigned)b)<<16);
}
__device__ __forceinline__ float blo(unsigned p){ return b2f((unsigned short)(p & 0xFFFF)); }
__device__ __forceinline__ float bhi(unsigned p){ return b2f((unsigned short)(p >> 16)); }
__device__ __forceinline__ unsigned hsh(int v){ return ((unsigned)v*2654435761u >> 21) & (HB-1); }

// blocks 0..3: WT transpose (+wa for 0,1); block 4: hash/bitmap/rep; blocks 5..12: zero cnt
__global__ void k_prep(const float* __restrict__ Wp, const float* __restrict__ Wc,
        const float* __restrict__ Wl, const float* __restrict__ Wr,
        const float* __restrict__ aspv, const float* __restrict__ adpv,
        const float* __restrict__ ascv, const float* __restrict__ adcv,
        const int* __restrict__ s, unsigned* __restrict__ bm,
        unsigned* __restrict__ hmap, int* __restrict__ rep, int* __restrict__ cnt,
        float* __restrict__ wa, unsigned short* __restrict__ WT4){
    int m = blockIdx.x, t = threadIdx.x;
    if (m >= 5){
        int b = m - 5;                    // 8 blocks zero cnt
        int per = (NSEG + 7)/8;
        for (int j = b*per + t; j < (b+1)*per && j < NSEG; j += 256) cnt[j] = 0;
        return;
    }
    if (m == 4){
        __shared__ int hk[HB];
        __shared__ int hv[HB];
        __shared__ unsigned bms[NBM];
        for (int j = t; j < HB; j += 256){ hk[j] = -1; hv[j] = 1<<30; }
        for (int j = t; j < NBM; j += 256) bms[j] = 0u;
        __syncthreads();
        for (int i = t; i < NSLOT; i += 256){
            int v = s[i];
            unsigned idx = hsh(v);
            while (true){
                int old = atomicCAS(&hk[idx], -1, v);
                if (old == -1 || old == v){ atomicMin(&hv[idx], i); break; }
                idx = (idx+1)&(HB-1);
            }
            atomicOr(&bms[v>>5], 1u << (v&31));
        }
        __syncthreads();
        for (int j = t; j < NBM; j += 256) bm[j] = bms[j];
        for (int j = t; j < HB; j += 256){
            int k = hk[j];
            hmap[j] = (k < 0) ? 0xFFFFFFFFu : (((unsigned)k << 10) | (unsigned)hv[j]);
        }
        for (int i = t; i < NSLOT; i += 256){
            int v = s[i];
            unsigned idx = hsh(v);
            while (hk[idx] != v) idx = (idx+1)&(HB-1);
            rep[i] = hv[idx];
        }
        return;
    }
    const float* W = (m==0) ? Wp : (m==1) ? Wc : (m==2) ? Wl : Wr;
    unsigned short* WT = WT4 + (size_t)m*DIM*DIM;
    if (m < 2 && t < DIM){
        const float* avs = m ? ascv : aspv;
        const float* avd = m ? adcv : adpv;
        float* wab = wa + m*2*DIM;
        float sv = 0.f, dv = 0.f;
        for (int n = 0; n < DIM; n++){
            float w = W[t*DIM + n];
            sv += w*avs[n]; dv += w*avd[n];
        }
        wab[t] = sv; wab[DIM + t] = dv;
    }
    for (int j = t; j < DIM*DIM; j += blockDim.x){
        int n = j >> 7, k = j & 127;
        WT[n*DIM + k] = f2b(W[k*DIM + n]);
    }
}

// wave per node: cast X row to bf16 + 4 attention scalars (f32 via wa)
__global__ __launch_bounds__(256) void k_cast(const float* __restrict__ X,
        const float* __restrict__ wa, unsigned* __restrict__ Xbf,
        float* __restrict__ asp, float* __restrict__ adp,
        float* __restrict__ asc, float* __restrict__ adc){
    int gw = (blockIdx.x*blockDim.x + threadIdx.x) >> 6;
    int lane = threadIdx.x & 63;
    if (gw >= NN) return;
    float2 x = *(const float2*)&X[(size_t)gw*DIM + lane*2];
    Xbf[(size_t)gw*64 + lane] = (unsigned)f2b(x.x) | ((unsigned)f2b(x.y) << 16);
    float sp = x.x*wa[2*lane]     + x.y*wa[2*lane+1];
    float dp = x.x*wa[128+2*lane] + x.y*wa[128+2*lane+1];
    float sc = x.x*wa[256+2*lane] + x.y*wa[256+2*lane+1];
    float dc = x.x*wa[384+2*lane] + x.y*wa[384+2*lane+1];
    #pragma unroll
    for (int off = 32; off; off >>= 1){
        sp += __shfl_xor(sp, off); dp += __shfl_xor(dp, off);
        sc += __shfl_xor(sc, off); dc += __shfl_xor(dc, off);
    }
    if (lane == 0){ asp[gw] = sp; adp[gw] = dp; asc[gw] = sc; adc[gw] = dc; }
}

// CSR build: (1) stream + LDS-queue matches, (2) drain with LDS hash lookup
__global__ __launch_bounds__(256) void k_build(const int* __restrict__ EI,
        const unsigned* __restrict__ bm, const unsigned* __restrict__ hmap,
        int* __restrict__ cnt, int* __restrict__ csr){
    __shared__ unsigned bms[NBM];
    __shared__ unsigned hm[HB];
    __shared__ unsigned q[QCAP];
    __shared__ int qn;
    for (int j = threadIdx.x; j < NBM; j += 256) bms[j] = bm[j];
    for (int j = threadIdx.x; j < HB; j += 256) hm[j] = hmap[j];
    if (threadIdx.x == 0) qn = 0;
    __syncthreads();
    const int Q = NE/4;
    const int G = gridDim.x*blockDim.x;
    int row = blockIdx.y;
    const int4* dstp = (const int4*)(EI + (size_t)(2*row+1)*NE);
    const int4* srcp = (const int4*)(EI + (size_t)(2*row)*NE);
    int tid = blockIdx.x*blockDim.x + threadIdx.x;
    #pragma unroll
    for (int u = 0; u < 4; u++){
        int ix = tid + u*G;
        if (ix < Q){
            int4 d = dstp[ix];
            unsigned m0 = (bms[d.x>>5] >> (d.x&31)) & 1u;
            unsigned m1 = (bms[d.y>>5] >> (d.y&31)) & 1u;
            unsigned m2 = (bms[d.z>>5] >> (d.z&31)) & 1u;
            unsigned m3 = (bms[d.w>>5] >> (d.w&31)) & 1u;
            if (m0|m1|m2|m3){
                int4 sv = srcp[ix];
                if (m0){ int p = atomicAdd(&qn,1); if (p < QCAP) q[p] = ((unsigned)d.x<<15) | (unsigned)sv.x; }
                if (m1){ int p = atomicAdd(&qn,1); if (p < QCAP) q[p] = ((unsigned)d.y<<15) | (unsigned)sv.y; }
                if (m2){ int p = atomicAdd(&qn,1); if (p < QCAP) q[p] = ((unsigned)d.z<<15) | (unsigned)sv.z; }
                if (m3){ int p = atomicAdd(&qn,1); if (p < QCAP) q[p] = ((unsigned)d.w<<15) | (unsigned)sv.w; }
            }
        }
    }
    __syncthreads();
    int base = row*NSLOT;
    int tot = qn; if (tot > QCAP) tot = QCAP;
    for (int j = threadIdx.x; j < tot; j += 256){
        unsigned e = q[j];
        int dst = (int)(e >> 15);
        int src = (int)(e & 32767u);
        unsigned idx = hsh(dst);
        unsigned he;
        while (((he = hm[idx]) >> 10) != (unsigned)dst) idx = (idx+1)&(HB-1);
        int sl = (int)(he & 1023u);
        int p = atomicAdd(&cnt[base+sl], 1);
        if (p < SEGCAP) csr[(size_t)(base+sl)*SEGCAP + p] = src;
    }
}

// wave per segment: weighted x-aggregation (GAT softmax weights or SAGE mean)
__global__ __launch_bounds__(256) void k_aggr(const unsigned* __restrict__ Xbf,
        const float* __restrict__ asp, const float* __restrict__ adp,
        const float* __restrict__ asc, const float* __restrict__ adc,
        const int* __restrict__ s, const int* __restrict__ cnt, const int* __restrict__ csr,
        unsigned* __restrict__ aggb){
    int gw = (blockIdx.x*blockDim.x + threadIdx.x) >> 6;
    int lane = threadIdx.x & 63;
    if (gw >= NSEG) return;
    int slot = gw & (NSLOT-1);
    int tg = gw >> 10;
    int g = tg % 3;
    int n = cnt[gw]; if (n > SEGCAP) n = SEGCAP;
    const int* lst = csr + (size_t)gw*SEGCAP;
    int src0 = (lane < n) ? lst[lane] : 0;
    int src1 = (64+lane < n) ? lst[64+lane] : 0;
    int n0 = n < 64 ? n : 64;
    float w0, w1, wself = 0.f, scale;
    int v = -1;
    if (g == 2){
        w0 = (lane < n) ? 1.f : 0.f;
        w1 = (64+lane < n) ? 1.f : 0.f;
        scale = 1.f / (float)(n > 0 ? n : 1);
    } else {
        const float* as = g ? asc : asp;
        const float* ad = g ? adc : adp;
        v = s[slot];
        float adv = ad[v];
        float eself = lrelu(as[v] + adv);
        float e0 = (lane < n)    ? lrelu(as[src0]+adv) : -3e38f;
        float e1 = (64+lane < n) ? lrelu(as[src1]+adv) : -3e38f;
        float m = fmaxf(eself, fmaxf(e0, e1));
        #pragma unroll
        for (int off = 32; off; off >>= 1) m = fmaxf(m, __shfl_xor(m, off));
        w0 = (lane < n)    ? __expf(e0 - m) : 0.f;
        w1 = (64+lane < n) ? __expf(e1 - m) : 0.f;
        float ds = w0 + w1;
        #pragma unroll
        for (int off = 32; off; off >>= 1) ds += __shfl_xor(ds, off);
        wself = __expf(eself - m);
        scale = 1.f / (wself + ds);
    }
    float a0 = 0.f, a1 = 0.f;
    int j = 0;
    for (; j+3 < n0; j += 4){
        int s0=__shfl(src0,j), s1=__shfl(src0,j+1), s2=__shfl(src0,j+2), s3=__shfl(src0,j+3);
        float q0=__shfl(w0,j), q1=__shfl(w0,j+1), q2=__shfl(w0,j+2), q3=__shfl(w0,j+3);
        unsigned k0=Xbf[(size_t)s0*64+lane];
        unsigned k1=Xbf[(size_t)s1*64+lane];
        unsigned k2=Xbf[(size_t)s2*64+lane];
        unsigned k3=Xbf[(size_t)s3*64+lane];
        a0 += q0*blo(k0) + q1*blo(k1) + q2*blo(k2) + q3*blo(k3);
        a1 += q0*bhi(k0) + q1*bhi(k1) + q2*bhi(k2) + q3*bhi(k3);
    }
    for (; j < n0; j++){
        int sj=__shfl(src0,j);
        float qj=__shfl(w0,j);
        unsigned pk=Xbf[(size_t)sj*64+lane];
        a0 += qj*blo(pk); a1 += qj*bhi(pk);
    }
    for (j = 64; j < n; j++){
        int sj=__shfl(src1,j-64);
        float qj=__shfl(w1,j-64);
        unsigned pk=Xbf[(size_t)sj*64+lane];
        a0 += qj*blo(pk); a1 += qj*bhi(pk);
    }
    if (g < 2){
        unsigned pk = Xbf[(size_t)v*64 + lane];
        a0 += wself*blo(pk); a1 += wself*bhi(pk);
    }
    aggb[(size_t)gw*64 + lane] =
        (unsigned)f2b(a0*scale) | ((unsigned)f2b(a1*scale) << 16);
}

// blocks 0..287: aggb rows @ W{p,c,l} -> aggOut; blocks 288..303: Xbf[s]@Wr -> xWr
__global__ __launch_bounds__(256) void k_sgemm(const unsigned* __restrict__ aggb,
        const unsigned* __restrict__ Xbf, const unsigned short* __restrict__ WT4,
        const int* __restrict__ s,
        float* __restrict__ aggOut, float* __restrict__ xWr){
    int task = (blockIdx.x >= 288);
    int blk  = task ? (blockIdx.x - 288) : blockIdx.x;
    int wsel = task ? 3 : ((blk >> 4) % 3);
    const unsigned short* WT = WT4 + (size_t)wsel*DIM*DIM;
    float* out = task ? xWr : aggOut;
    int rows = task ? NSLOT : NSEG;
    int wid = threadIdx.x >> 6, lane = threadIdx.x & 63;
    int r0 = blk*64 + wid*16;
    int ar = r0 + (lane & 15); if (ar > rows-1) ar = rows-1;
    int g = lane >> 4;
    const unsigned short* Arow = task
        ? (const unsigned short*)(Xbf + (size_t)s[ar]*64)
        : (const unsigned short*)(aggb + (size_t)ar*64);
    bf16x8 Af[4];
    #pragma unroll
    for (int ks = 0; ks < 4; ks++)
        Af[ks] = *(const bf16x8*)&Arow[ks*32 + g*8];
    int cl = lane & 15;
    #pragma unroll
    for (int ct = 0; ct < 8; ct++){
        f32x4 acc = {0.f,0.f,0.f,0.f};
        int bcol = ct*16 + cl;
        #pragma unroll
        for (int ks = 0; ks < 4; ks++){
            bf16x8 bF = *(const bf16x8*)&WT[bcol*DIM + ks*32 + g*8];
            acc = __builtin_amdgcn_mfma_f32_16x16x32_bf16(Af[ks], bF, acc, 0, 0, 0);
        }
        #pragma unroll
        for (int r = 0; r < 4; r++){
            int row = r0 + g*4 + r;
            if (row < rows) out[(size_t)row*DIM + bcol] = acc[r];
        }
    }
}

__global__ void k_gather(const int* __restrict__ rep,
                         const float* __restrict__ aggOut, const float* __restrict__ xWr,
                         const float* __restrict__ bp, const float* __restrict__ bc,
                         const float* __restrict__ bl, const float* __restrict__ br,
                         float* __restrict__ out){
    int i = blockIdx.x*blockDim.x + threadIdx.x;
    if (i >= NT*NSLOT*DIM) return;
    int d = i & 127;
    int r = (i >> 7) & (NSLOT-1);
    int t = i >> 17;
    int rp = rep[r];
    size_t base = ((size_t)(t*3)*NSLOT + rp)*DIM + d;
    out[i] = (aggOut[base] + aggOut[base + NSLOT*DIM] + aggOut[base + 2*NSLOT*DIM]
              + xWr[(size_t)rp*DIM + d]
              + bp[d] + bc[d] + bl[d] + br[d]) * (1.f/3.f);
}

extern "C" void kernel_launch(void* const* d_in, const int* in_sizes, int n_in,
                              void* d_out, int out_size, void* d_ws, size_t ws_size,
                              hipStream_t stream) {
    const int*   s    = (const int*)d_in[0];
    const int*   EI   = (const int*)d_in[3];
    const float* X    = (const float*)d_in[4];
    const float* Wp   = (const float*)d_in[5];
    const float* aspv = (const float*)d_in[6];
    const float* adpv = (const float*)d_in[7];
    const float* bp   = (const float*)d_in[8];
    const float* Wc   = (const float*)d_in[9];
    const float* ascv = (const float*)d_in[10];
    const float* adcv = (const float*)d_in[11];
    const float* bc   = (const float*)d_in[12];
    const float* Wl   = (const float*)d_in[13];
    const float* bl   = (const float*)d_in[14];
    const float* Wr   = (const float*)d_in[15];
    const float* br   = (const float*)d_in[16];
    float* out = (float*)d_out;

    char* w = (char*)d_ws;
    unsigned* Xbf = (unsigned*)w; w += (size_t)NN*64*4;
    unsigned short* WT4 = (unsigned short*)w; w += (size_t)4*DIM*DIM*2;
    float* wa  = (float*)w; w += (size_t)4*DIM*4;
    float* asp = (float*)w; w += (size_t)NN*4;
    float* adp = (float*)w; w += (size_t)NN*4;
    float* asc = (float*)w; w += (size_t)NN*4;
    float* adc = (float*)w; w += (size_t)NN*4;
    unsigned* bm = (unsigned*)w; w += (size_t)((NBM+3)&~3)*4;
    unsigned* hmap = (unsigned*)w; w += (size_t)HB*4;
    int* rep  = (int*)w; w += (size_t)NSLOT*4;
    int* cnt  = (int*)w; w += (size_t)NSEG*4;
    int* csr  = (int*)w; w += (size_t)NSEG*SEGCAP*4;
    unsigned* aggb = (unsigned*)w; w += (size_t)NSEG*64*4;
    float* aggOut = (float*)w; w += (size_t)NSEG*DIM*4;
    float* xWr = (float*)w; w += (size_t)NSLOT*DIM*4;

    k_prep   <<<13, 256, 0, stream>>>(Wp, Wc, Wl, Wr, aspv, adpv, ascv, adcv,
                                      s, bm, hmap, rep, cnt, wa, WT4);
    k_cast   <<<(NN+3)/4, 256, 0, stream>>>(X, wa, Xbf, asp, adp, asc, adc);
    k_build  <<<dim3(118, 18), 256, 0, stream>>>(EI, bm, hmap, cnt, csr);
    k_aggr   <<<NSEG/4, 256, 0, stream>>>(Xbf, asp, adp, asc, adc, s, cnt, csr, aggb);
    k_sgemm  <<<304, 256, 0, stream>>>(aggb, Xbf, WT4, s, aggOut, xWr);
    k_gather <<<NT*NSLOT*DIM/256, 256, 0, stream>>>(rep, aggOut, xWr, bp, bc, bl, br, out);
}

// Round 10
// 84.677 us; speedup vs baseline: 1.8186x; 1.0779x over previous
//
#include <hip/hip_runtime.h>
#include <hip/hip_bf16.h>

#define NN 30000
#define DIM 128
#define NT 6
#define NE 480000
#define NSLOT 1024
#define NSEG (NT*3*NSLOT)   // 18432
#define SEGCAP 96
#define NBM ((NN+31)/32)    // 938
#define QCAP 2048
#define HB 2048             // hash slots

typedef __attribute__((ext_vector_type(8))) short bf16x8;
typedef __attribute__((ext_vector_type(4))) float f32x4;

__device__ __forceinline__ float lrelu(float x){ return x > 0.f ? x : 0.2f*x; }
__device__ __forceinline__ unsigned short f2b(float f){
    unsigned u = __float_as_uint(f);
    u = (u + 0x7FFFu + ((u>>16)&1u)) >> 16;
    return (unsigned short)u;
}
__device__ __forceinline__ float b2f(unsigned short b){
    return __uint_as_float(((unsigned)b)<<16);
}
__device__ __forceinline__ float blo(unsigned p){ return b2f((unsigned short)(p & 0xFFFF)); }
__device__ __forceinline__ float bhi(unsigned p){ return b2f((unsigned short)(p >> 16)); }
__device__ __forceinline__ unsigned hsh(int v){ return ((unsigned)v*2654435761u >> 21) & (HB-1); }

// blocks 0..3: WT transpose (+wa for 0,1); block 4: hash/bitmap/rep; blocks 5..12: zero cnt
__global__ void k_prep(const float* __restrict__ Wp, const float* __restrict__ Wc,
        const float* __restrict__ Wl, const float* __restrict__ Wr,
        const float* __restrict__ aspv, const float* __restrict__ adpv,
        const float* __restrict__ ascv, const float* __restrict__ adcv,
        const int* __restrict__ s, unsigned* __restrict__ bm,
        unsigned* __restrict__ hmap, int* __restrict__ rep, int* __restrict__ cnt,
        float* __restrict__ wa, unsigned short* __restrict__ WT4){
    int m = blockIdx.x, t = threadIdx.x;
    if (m >= 5){
        int b = m - 5;
        int per = (NSEG + 7)/8;
        for (int j = b*per + t; j < (b+1)*per && j < NSEG; j += 256) cnt[j] = 0;
        return;
    }
    if (m == 4){
        __shared__ int hk[HB];
        __shared__ int hv[HB];
        __shared__ unsigned bms[NBM];
        for (int j = t; j < HB; j += 256){ hk[j] = -1; hv[j] = 1<<30; }
        for (int j = t; j < NBM; j += 256) bms[j] = 0u;
        __syncthreads();
        for (int i = t; i < NSLOT; i += 256){
            int v = s[i];
            unsigned idx = hsh(v);
            while (true){
                int old = atomicCAS(&hk[idx], -1, v);
                if (old == -1 || old == v){ atomicMin(&hv[idx], i); break; }
                idx = (idx+1)&(HB-1);
            }
            atomicOr(&bms[v>>5], 1u << (v&31));
        }
        __syncthreads();
        for (int j = t; j < NBM; j += 256) bm[j] = bms[j];
        for (int j = t; j < HB; j += 256){
            int k = hk[j];
            hmap[j] = (k < 0) ? 0xFFFFFFFFu : (((unsigned)k << 10) | (unsigned)hv[j]);
        }
        for (int i = t; i < NSLOT; i += 256){
            int v = s[i];
            unsigned idx = hsh(v);
            while (hk[idx] != v) idx = (idx+1)&(HB-1);
            rep[i] = hv[idx];
        }
        return;
    }
    const float* W = (m==0) ? Wp : (m==1) ? Wc : (m==2) ? Wl : Wr;
    unsigned short* WT = WT4 + (size_t)m*DIM*DIM;
    if (m < 2 && t < DIM){
        const float* avs = m ? ascv : aspv;
        const float* avd = m ? adcv : adpv;
        float* wab = wa + m*2*DIM;
        float sv = 0.f, dv = 0.f;
        for (int n = 0; n < DIM; n++){
            float w = W[t*DIM + n];
            sv += w*avs[n]; dv += w*avd[n];
        }
        wab[t] = sv; wab[DIM + t] = dv;
    }
    for (int j = t; j < DIM*DIM; j += blockDim.x){
        int n = j >> 7, k = j & 127;
        WT[n*DIM + k] = f2b(W[k*DIM + n]);
    }
}

// wave per node: cast X row to bf16 + 4 attention scalars (f32 via wa)
__global__ __launch_bounds__(256) void k_cast(const float* __restrict__ X,
        const float* __restrict__ wa, unsigned* __restrict__ Xbf,
        float* __restrict__ asp, float* __restrict__ adp,
        float* __restrict__ asc, float* __restrict__ adc){
    int gw = (blockIdx.x*blockDim.x + threadIdx.x) >> 6;
    int lane = threadIdx.x & 63;
    if (gw >= NN) return;
    float2 x = *(const float2*)&X[(size_t)gw*DIM + lane*2];
    Xbf[(size_t)gw*64 + lane] = (unsigned)f2b(x.x) | ((unsigned)f2b(x.y) << 16);
    float sp = x.x*wa[2*lane]     + x.y*wa[2*lane+1];
    float dp = x.x*wa[128+2*lane] + x.y*wa[128+2*lane+1];
    float sc = x.x*wa[256+2*lane] + x.y*wa[256+2*lane+1];
    float dc = x.x*wa[384+2*lane] + x.y*wa[384+2*lane+1];
    #pragma unroll
    for (int off = 32; off; off >>= 1){
        sp += __shfl_xor(sp, off); dp += __shfl_xor(dp, off);
        sc += __shfl_xor(sc, off); dc += __shfl_xor(dc, off);
    }
    if (lane == 0){ asp[gw] = sp; adp[gw] = dp; asc[gw] = sc; adc[gw] = dc; }
}

// CSR build: (1) stream + ballot-compacted LDS-queue, (2) lane-parallel drain (global hash)
__global__ __launch_bounds__(256) void k_build(const int* __restrict__ EI,
        const unsigned* __restrict__ bm, const unsigned* __restrict__ hmap,
        int* __restrict__ cnt, int* __restrict__ csr){
    __shared__ unsigned bms[NBM];
    __shared__ unsigned q[QCAP];
    __shared__ int qn;
    for (int j = threadIdx.x; j < NBM; j += 256) bms[j] = bm[j];
    if (threadIdx.x == 0) qn = 0;
    __syncthreads();
    const int Q = NE/4;
    const int G = gridDim.x*blockDim.x;
    int row = blockIdx.y;
    const int4* dstp = (const int4*)(EI + (size_t)(2*row+1)*NE);
    const int4* srcp = (const int4*)(EI + (size_t)(2*row)*NE);
    int tid = blockIdx.x*blockDim.x + threadIdx.x;
    int lane = threadIdx.x & 63;

    int4 d[4]; int ix[4]; bool va[4];
    #pragma unroll
    for (int u = 0; u < 4; u++){
        ix[u] = tid + u*G;
        va[u] = ix[u] < Q;
        d[u] = va[u] ? dstp[ix[u]] : make_int4(0,0,0,0);
    }
    unsigned mk[4];
    #pragma unroll
    for (int u = 0; u < 4; u++){
        unsigned m0 = va[u] ? ((bms[d[u].x>>5] >> (d[u].x&31)) & 1u) : 0u;
        unsigned m1 = va[u] ? ((bms[d[u].y>>5] >> (d[u].y&31)) & 1u) : 0u;
        unsigned m2 = va[u] ? ((bms[d[u].z>>5] >> (d[u].z&31)) & 1u) : 0u;
        unsigned m3 = va[u] ? ((bms[d[u].w>>5] >> (d[u].w&31)) & 1u) : 0u;
        mk[u] = m0 | (m1<<1) | (m2<<2) | (m3<<3);
    }
    int4 sv[4];
    #pragma unroll
    for (int u = 0; u < 4; u++)
        if (mk[u]) sv[u] = srcp[ix[u]];
    #pragma unroll
    for (int u = 0; u < 4; u++){
        #pragma unroll
        for (int c = 0; c < 4; c++){
            bool p = (mk[u] >> c) & 1u;
            unsigned long long bal = __ballot(p);
            if (bal){
                int cntw = __popcll(bal);
                int base = 0;
                if (lane == 0) base = atomicAdd(&qn, cntw);
                base = __shfl(base, 0);
                if (p){
                    int dv = (c==0)?d[u].x:(c==1)?d[u].y:(c==2)?d[u].z:d[u].w;
                    int so = (c==0)?sv[u].x:(c==1)?sv[u].y:(c==2)?sv[u].z:sv[u].w;
                    int pos = base + __popcll(bal & ((1ull<<lane)-1ull));
                    if (pos < QCAP) q[pos] = ((unsigned)dv<<15) | (unsigned)so;
                }
            }
        }
    }
    __syncthreads();
    int base = row*NSLOT;
    int tot = qn; if (tot > QCAP) tot = QCAP;
    for (int j = threadIdx.x; j < tot; j += 256){
        unsigned e = q[j];
        int dst = (int)(e >> 15);
        int src = (int)(e & 32767u);
        unsigned idx = hsh(dst);
        unsigned he;
        while (((he = hmap[idx]) >> 10) != (unsigned)dst) idx = (idx+1)&(HB-1);
        int sl = (int)(he & 1023u);
        int p = atomicAdd(&cnt[base+sl], 1);
        if (p < SEGCAP) csr[(size_t)(base+sl)*SEGCAP + p] = src;
    }
}

// wave per segment: weighted x-aggregation (GAT softmax weights or SAGE mean); unroll-8
__global__ __launch_bounds__(256) void k_aggr(const unsigned* __restrict__ Xbf,
        const float* __restrict__ asp, const float* __restrict__ adp,
        const float* __restrict__ asc, const float* __restrict__ adc,
        const int* __restrict__ s, const int* __restrict__ cnt, const int* __restrict__ csr,
        unsigned* __restrict__ aggb){
    int gw = (blockIdx.x*blockDim.x + threadIdx.x) >> 6;
    int lane = threadIdx.x & 63;
    if (gw >= NSEG) return;
    int slot = gw & (NSLOT-1);
    int tg = gw >> 10;
    int g = tg % 3;
    int n = cnt[gw]; if (n > SEGCAP) n = SEGCAP;
    const int* lst = csr + (size_t)gw*SEGCAP;
    int src0 = (lane < n) ? lst[lane] : 0;
    int src1 = (64+lane < n) ? lst[64+lane] : 0;
    int n0 = n < 64 ? n : 64;
    float w0, w1, wself = 0.f, scale;
    int v = -1;
    if (g == 2){
        w0 = (lane < n) ? 1.f : 0.f;
        w1 = (64+lane < n) ? 1.f : 0.f;
        scale = 1.f / (float)(n > 0 ? n : 1);
    } else {
        const float* as = g ? asc : asp;
        const float* ad = g ? adc : adp;
        v = s[slot];
        float adv = ad[v];
        float eself = lrelu(as[v] + adv);
        float e0 = (lane < n)    ? lrelu(as[src0]+adv) : -3e38f;
        float e1 = (64+lane < n) ? lrelu(as[src1]+adv) : -3e38f;
        float m = fmaxf(eself, fmaxf(e0, e1));
        #pragma unroll
        for (int off = 32; off; off >>= 1) m = fmaxf(m, __shfl_xor(m, off));
        w0 = (lane < n)    ? __expf(e0 - m) : 0.f;
        w1 = (64+lane < n) ? __expf(e1 - m) : 0.f;
        float ds = w0 + w1;
        #pragma unroll
        for (int off = 32; off; off >>= 1) ds += __shfl_xor(ds, off);
        wself = __expf(eself - m);
        scale = 1.f / (wself + ds);
    }
    float a0 = 0.f, a1 = 0.f;
    int j = 0;
    for (; j+7 < n0; j += 8){
        int   si[8]; float qi[8]; unsigned ki[8];
        #pragma unroll
        for (int u = 0; u < 8; u++){ si[u] = __shfl(src0, j+u); qi[u] = __shfl(w0, j+u); }
        #pragma unroll
        for (int u = 0; u < 8; u++) ki[u] = Xbf[(size_t)si[u]*64 + lane];
        #pragma unroll
        for (int u = 0; u < 8; u++){ a0 += qi[u]*blo(ki[u]); a1 += qi[u]*bhi(ki[u]); }
    }
    for (; j+3 < n0; j += 4){
        int s0=__shfl(src0,j), s1=__shfl(src0,j+1), s2=__shfl(src0,j+2), s3=__shfl(src0,j+3);
        float q0=__shfl(w0,j), q1=__shfl(w0,j+1), q2=__shfl(w0,j+2), q3=__shfl(w0,j+3);
        unsigned k0=Xbf[(size_t)s0*64+lane];
        unsigned k1=Xbf[(size_t)s1*64+lane];
        unsigned k2=Xbf[(size_t)s2*64+lane];
        unsigned k3=Xbf[(size_t)s3*64+lane];
        a0 += q0*blo(k0) + q1*blo(k1) + q2*blo(k2) + q3*blo(k3);
        a1 += q0*bhi(k0) + q1*bhi(k1) + q2*bhi(k2) + q3*bhi(k3);
    }
    for (; j < n0; j++){
        int sj=__shfl(src0,j);
        float qj=__shfl(w0,j);
        unsigned pk=Xbf[(size_t)sj*64+lane];
        a0 += qj*blo(pk); a1 += qj*bhi(pk);
    }
    for (j = 64; j < n; j++){
        int sj=__shfl(src1,j-64);
        float qj=__shfl(w1,j-64);
        unsigned pk=Xbf[(size_t)sj*64+lane];
        a0 += qj*blo(pk); a1 += qj*bhi(pk);
    }
    if (g < 2){
        unsigned pk = Xbf[(size_t)v*64 + lane];
        a0 += wself*blo(pk); a1 += wself*bhi(pk);
    }
    aggb[(size_t)gw*64 + lane] =
        (unsigned)f2b(a0*scale) | ((unsigned)f2b(a1*scale) << 16);
}

// blocks 0..287: aggb rows @ W{p,c,l} -> aggOut; blocks 288..303: Xbf[s]@Wr -> xWr
__global__ __launch_bounds__(256) void k_sgemm(const unsigned* __restrict__ aggb,
        const unsigned* __restrict__ Xbf, const unsigned short* __restrict__ WT4,
        const int* __restrict__ s,
        float* __restrict__ aggOut, float* __restrict__ xWr){
    int task = (blockIdx.x >= 288);
    int blk  = task ? (blockIdx.x - 288) : blockIdx.x;
    int wsel = task ? 3 : ((blk >> 4) % 3);
    const unsigned short* WT = WT4 + (size_t)wsel*DIM*DIM;
    float* out = task ? xWr : aggOut;
    int rows = task ? NSLOT : NSEG;
    int wid = threadIdx.x >> 6, lane = threadIdx.x & 63;
    int r0 = blk*64 + wid*16;
    int ar = r0 + (lane & 15); if (ar > rows-1) ar = rows-1;
    int g = lane >> 4;
    const unsigned short* Arow = task
        ? (const unsigned short*)(Xbf + (size_t)s[ar]*64)
        : (const unsigned short*)(aggb + (size_t)ar*64);
    bf16x8 Af[4];
    #pragma unroll
    for (int ks = 0; ks < 4; ks++)
        Af[ks] = *(const bf16x8*)&Arow[ks*32 + g*8];
    int cl = lane & 15;
    #pragma unroll
    for (int ct = 0; ct < 8; ct++){
        f32x4 acc = {0.f,0.f,0.f,0.f};
        int bcol = ct*16 + cl;
        #pragma unroll
        for (int ks = 0; ks < 4; ks++){
            bf16x8 bF = *(const bf16x8*)&WT[bcol*DIM + ks*32 + g*8];
            acc = __builtin_amdgcn_mfma_f32_16x16x32_bf16(Af[ks], bF, acc, 0, 0, 0);
        }
        #pragma unroll
        for (int r = 0; r < 4; r++){
            int row = r0 + g*4 + r;
            if (row < rows) out[(size_t)row*DIM + bcol] = acc[r];
        }
    }
}

__global__ void k_gather(const int* __restrict__ rep,
                         const float* __restrict__ aggOut, const float* __restrict__ xWr,
                         const float* __restrict__ bp, const float* __restrict__ bc,
                         const float* __restrict__ bl, const float* __restrict__ br,
                         float* __restrict__ out){
    int i = blockIdx.x*blockDim.x + threadIdx.x;
    if (i >= NT*NSLOT*DIM) return;
    int d = i & 127;
    int r = (i >> 7) & (NSLOT-1);
    int t = i >> 17;
    int rp = rep[r];
    size_t base = ((size_t)(t*3)*NSLOT + rp)*DIM + d;
    out[i] = (aggOut[base] + aggOut[base + NSLOT*DIM] + aggOut[base + 2*NSLOT*DIM]
              + xWr[(size_t)rp*DIM + d]
              + bp[d] + bc[d] + bl[d] + br[d]) * (1.f/3.f);
}

extern "C" void kernel_launch(void* const* d_in, const int* in_sizes, int n_in,
                              void* d_out, int out_size, void* d_ws, size_t ws_size,
                              hipStream_t stream) {
    const int*   s    = (const int*)d_in[0];
    const int*   EI   = (const int*)d_in[3];
    const float* X    = (const float*)d_in[4];
    const float* Wp   = (const float*)d_in[5];
    const float* aspv = (const float*)d_in[6];
    const float* adpv = (const float*)d_in[7];
    const float* bp   = (const float*)d_in[8];
    const float* Wc   = (const float*)d_in[9];
    const float* ascv = (const float*)d_in[10];
    const float* adcv = (const float*)d_in[11];
    const float* bc   = (const float*)d_in[12];
    const float* Wl   = (const float*)d_in[13];
    const float* bl   = (const float*)d_in[14];
    const float* Wr   = (const float*)d_in[15];
    const float* br   = (const float*)d_in[16];
    float* out = (float*)d_out;

    char* w = (char*)d_ws;
    unsigned* Xbf = (unsigned*)w; w += (size_t)NN*64*4;
    unsigned short* WT4 = (unsigned short*)w; w += (size_t)4*DIM*DIM*2;
    float* wa  = (float*)w; w += (size_t)4*DIM*4;
    float* asp = (float*)w; w += (size_t)NN*4;
    float* adp = (float*)w; w += (size_t)NN*4;
    float* asc = (float*)w; w += (size_t)NN*4;
    float* adc = (float*)w; w += (size_t)NN*4;
    unsigned* bm = (unsigned*)w; w += (size_t)((NBM+3)&~3)*4;
    unsigned* hmap = (unsigned*)w; w += (size_t)HB*4;
    int* rep  = (int*)w; w += (size_t)NSLOT*4;
    int* cnt  = (int*)w; w += (size_t)NSEG*4;
    int* csr  = (int*)w; w += (size_t)NSEG*SEGCAP*4;
    unsigned* aggb = (unsigned*)w; w += (size_t)NSEG*64*4;
    float* aggOut = (float*)w; w += (size_t)NSEG*DIM*4;
    float* xWr = (float*)w; w += (size_t)NSLOT*DIM*4;

    k_prep   <<<13, 256, 0, stream>>>(Wp, Wc, Wl, Wr, aspv, adpv, ascv, adcv,
                                      s, bm, hmap, rep, cnt, wa, WT4);
    k_cast   <<<(NN+3)/4, 256, 0, stream>>>(X, wa, Xbf, asp, adp, asc, adc);
    k_build  <<<dim3(118, 18), 256, 0, stream>>>(EI, bm, hmap, cnt, csr);
    k_aggr   <<<NSEG/4, 256, 0, stream>>>(Xbf, asp, adp, asc, adc, s, cnt, csr, aggb);
    k_sgemm  <<<304, 256, 0, stream>>>(aggb, Xbf, WT4, s, aggOut, xWr);
    k_gather <<<NT*NSLOT*DIM/256, 256, 0, stream>>>(rep, aggOut, xWr, bp, bc, bl, br, out);
}

// Round 11
// 75.431 us; speedup vs baseline: 2.0415x; 1.1226x over previous
//
#include <hip/hip_runtime.h>
#include <hip/hip_bf16.h>

#define NN 30000
#define DIM 128
#define NT 6
#define NE 480000
#define NSLOT 1024
#define NSEG (NT*3*NSLOT)   // 18432
#define SEGCAP 96
#define NBM ((NN+31)/32)    // 938
#define QCAP 2048
#define HB 2048
#define NBUILD 2124         // 118*18
#define NCAST 876
#define NAGG (NSEG/16)      // 1152

typedef __attribute__((ext_vector_type(8))) short bf16x8;
typedef __attribute__((ext_vector_type(4))) float f32x4;

__device__ __forceinline__ float lrelu(float x){ return x > 0.f ? x : 0.2f*x; }
__device__ __forceinline__ unsigned short f2b(float f){
    unsigned u = __float_as_uint(f);
    u = (u + 0x7FFFu + ((u>>16)&1u)) >> 16;
    return (unsigned short)u;
}
__device__ __forceinline__ float b2f(unsigned short b){
    return __uint_as_float(((unsigned)b)<<16);
}
__device__ __forceinline__ float blo(unsigned p){ return b2f((unsigned short)(p & 0xFFFF)); }
__device__ __forceinline__ float bhi(unsigned p){ return b2f((unsigned short)(p >> 16)); }
__device__ __forceinline__ unsigned hsh(int v){ return ((unsigned)v*2654435761u >> 21) & (HB-1); }

// blocks 0..3: WT transpose (+wa for 0,1); block 4: hash/bitmap/rep; blocks 5..12: zero cnt
__global__ void k_prep(const float* __restrict__ Wp, const float* __restrict__ Wc,
        const float* __restrict__ Wl, const float* __restrict__ Wr,
        const float* __restrict__ aspv, const float* __restrict__ adpv,
        const float* __restrict__ ascv, const float* __restrict__ adcv,
        const int* __restrict__ s, unsigned* __restrict__ bm,
        unsigned* __restrict__ hmap, int* __restrict__ rep, int* __restrict__ cnt,
        float* __restrict__ wa, unsigned short* __restrict__ WT4){
    int m = blockIdx.x, t = threadIdx.x;
    if (m >= 5){
        int b = m - 5;
        int per = (NSEG + 7)/8;
        for (int j = b*per + t; j < (b+1)*per && j < NSEG; j += 256) cnt[j] = 0;
        return;
    }
    if (m == 4){
        __shared__ int hk[HB];
        __shared__ int hv[HB];
        __shared__ unsigned bms[NBM];
        for (int j = t; j < HB; j += 256){ hk[j] = -1; hv[j] = 1<<30; }
        for (int j = t; j < NBM; j += 256) bms[j] = 0u;
        __syncthreads();
        for (int i = t; i < NSLOT; i += 256){
            int v = s[i];
            unsigned idx = hsh(v);
            while (true){
                int old = atomicCAS(&hk[idx], -1, v);
                if (old == -1 || old == v){ atomicMin(&hv[idx], i); break; }
                idx = (idx+1)&(HB-1);
            }
            atomicOr(&bms[v>>5], 1u << (v&31));
        }
        __syncthreads();
        for (int j = t; j < NBM; j += 256) bm[j] = bms[j];
        for (int j = t; j < HB; j += 256){
            int k = hk[j];
            hmap[j] = (k < 0) ? 0xFFFFFFFFu : (((unsigned)k << 10) | (unsigned)hv[j]);
        }
        for (int i = t; i < NSLOT; i += 256){
            int v = s[i];
            unsigned idx = hsh(v);
            while (hk[idx] != v) idx = (idx+1)&(HB-1);
            rep[i] = hv[idx];
        }
        return;
    }
    const float* W = (m==0) ? Wp : (m==1) ? Wc : (m==2) ? Wl : Wr;
    unsigned short* WT = WT4 + (size_t)m*DIM*DIM;
    if (m < 2 && t < DIM){
        const float* avs = m ? ascv : aspv;
        const float* avd = m ? adcv : adpv;
        float* wab = wa + m*2*DIM;
        float sv = 0.f, dv = 0.f;
        for (int n = 0; n < DIM; n++){
            float w = W[t*DIM + n];
            sv += w*avs[n]; dv += w*avd[n];
        }
        wab[t] = sv; wab[DIM + t] = dv;
    }
    for (int j = t; j < DIM*DIM; j += blockDim.x){
        int n = j >> 7, k = j & 127;
        WT[n*DIM + k] = f2b(W[k*DIM + n]);
    }
}

// blocks [0,NCAST): cast (grid-stride, wave/node); [NCAST, NCAST+NBUILD): CSR build
__global__ __launch_bounds__(256) void k_castbuild(
        const float* __restrict__ X, const float* __restrict__ wa,
        unsigned* __restrict__ Xbf,
        float* __restrict__ asp, float* __restrict__ adp,
        float* __restrict__ asc, float* __restrict__ adc,
        const int* __restrict__ EI,
        const unsigned* __restrict__ bm, const unsigned* __restrict__ hmap,
        int* __restrict__ cnt, int* __restrict__ csr){
    __shared__ unsigned bms[NBM];
    __shared__ unsigned q[QCAP];
    __shared__ int qn;
    int bx = blockIdx.x;
    int lane = threadIdx.x & 63;
    int wib = threadIdx.x >> 6;
    if (bx < NCAST){
        for (int node = bx*4 + wib; node < NN; node += NCAST*4){
            float2 x = *(const float2*)&X[(size_t)node*DIM + lane*2];
            Xbf[(size_t)node*64 + lane] = (unsigned)f2b(x.x) | ((unsigned)f2b(x.y) << 16);
            float sp = x.x*wa[2*lane]     + x.y*wa[2*lane+1];
            float dp = x.x*wa[128+2*lane] + x.y*wa[128+2*lane+1];
            float sc = x.x*wa[256+2*lane] + x.y*wa[256+2*lane+1];
            float dc = x.x*wa[384+2*lane] + x.y*wa[384+2*lane+1];
            #pragma unroll
            for (int off = 32; off; off >>= 1){
                sp += __shfl_xor(sp, off); dp += __shfl_xor(dp, off);
                sc += __shfl_xor(sc, off); dc += __shfl_xor(dc, off);
            }
            if (lane == 0){ asp[node]=sp; adp[node]=dp; asc[node]=sc; adc[node]=dc; }
        }
        return;
    }
    int bb = bx - NCAST;
    int row = bb / 118, bxx = bb - row*118;
    for (int j = threadIdx.x; j < NBM; j += 256) bms[j] = bm[j];
    if (threadIdx.x == 0) qn = 0;
    __syncthreads();
    const int Q = NE/4;
    const int G = 118*256;
    const int4* dstp = (const int4*)(EI + (size_t)(2*row+1)*NE);
    const int4* srcp = (const int4*)(EI + (size_t)(2*row)*NE);
    int tid = bxx*256 + threadIdx.x;

    int4 d[4]; int ix[4]; bool va[4];
    #pragma unroll
    for (int u = 0; u < 4; u++){
        ix[u] = tid + u*G;
        va[u] = ix[u] < Q;
        d[u] = va[u] ? dstp[ix[u]] : make_int4(0,0,0,0);
    }
    unsigned mk[4];
    #pragma unroll
    for (int u = 0; u < 4; u++){
        unsigned m0 = va[u] ? ((bms[d[u].x>>5] >> (d[u].x&31)) & 1u) : 0u;
        unsigned m1 = va[u] ? ((bms[d[u].y>>5] >> (d[u].y&31)) & 1u) : 0u;
        unsigned m2 = va[u] ? ((bms[d[u].z>>5] >> (d[u].z&31)) & 1u) : 0u;
        unsigned m3 = va[u] ? ((bms[d[u].w>>5] >> (d[u].w&31)) & 1u) : 0u;
        mk[u] = m0 | (m1<<1) | (m2<<2) | (m3<<3);
    }
    int4 sv[4];
    #pragma unroll
    for (int u = 0; u < 4; u++)
        if (mk[u]) sv[u] = srcp[ix[u]];
    #pragma unroll
    for (int u = 0; u < 4; u++){
        #pragma unroll
        for (int c = 0; c < 4; c++){
            bool p = (mk[u] >> c) & 1u;
            unsigned long long bal = __ballot(p);
            if (bal){
                int cntw = __popcll(bal);
                int base = 0;
                if (lane == 0) base = atomicAdd(&qn, cntw);
                base = __shfl(base, 0);
                if (p){
                    int dv = (c==0)?d[u].x:(c==1)?d[u].y:(c==2)?d[u].z:d[u].w;
                    int so = (c==0)?sv[u].x:(c==1)?sv[u].y:(c==2)?sv[u].z:sv[u].w;
                    int pos = base + __popcll(bal & ((1ull<<lane)-1ull));
                    if (pos < QCAP) q[pos] = ((unsigned)dv<<15) | (unsigned)so;
                }
            }
        }
    }
    __syncthreads();
    int base = row*NSLOT;
    int tot = qn; if (tot > QCAP) tot = QCAP;
    for (int j = threadIdx.x; j < tot; j += 256){
        unsigned e = q[j];
        int dst = (int)(e >> 15);
        int src = (int)(e & 32767u);
        unsigned idx = hsh(dst);
        unsigned he;
        while (((he = hmap[idx]) >> 10) != (unsigned)dst) idx = (idx+1)&(HB-1);
        int sl = (int)(he & 1023u);
        int p = atomicAdd(&cnt[base+sl], 1);
        if (p < SEGCAP) csr[(size_t)(base+sl)*SEGCAP + p] = src;
    }
}

// blocks [0,NAGG): 16 segments/block -> aggregate to LDS -> 16x128x128 MFMA -> aggOut
// blocks [NAGG, NAGG+16): Xbf[s]@WrT -> xWr
__global__ __launch_bounds__(256) void k_aggemm(const unsigned* __restrict__ Xbf,
        const float* __restrict__ asp, const float* __restrict__ adp,
        const float* __restrict__ asc, const float* __restrict__ adc,
        const int* __restrict__ s, const int* __restrict__ cnt, const int* __restrict__ csr,
        const unsigned short* __restrict__ WT4,
        float* __restrict__ aggOut, float* __restrict__ xWr){
    __shared__ unsigned tile[16][72];   // 288B row: 16B-aligned, low-conflict
    int bx = blockIdx.x;
    int lane = threadIdx.x & 63;
    int wib = threadIdx.x >> 6;
    if (bx >= NAGG){
        int blk = bx - NAGG;
        const unsigned short* WT = WT4 + (size_t)3*DIM*DIM;
        int r0 = blk*64 + wib*16;
        int ar = r0 + (lane & 15); if (ar > NSLOT-1) ar = NSLOT-1;
        int g4 = lane >> 4;
        const unsigned short* Arow = (const unsigned short*)(Xbf + (size_t)s[ar]*64);
        bf16x8 Af[4];
        #pragma unroll
        for (int ks = 0; ks < 4; ks++)
            Af[ks] = *(const bf16x8*)&Arow[ks*32 + g4*8];
        int cl = lane & 15;
        #pragma unroll
        for (int ct = 0; ct < 8; ct++){
            f32x4 acc = {0.f,0.f,0.f,0.f};
            int bcol = ct*16 + cl;
            #pragma unroll
            for (int ks = 0; ks < 4; ks++){
                bf16x8 bF = *(const bf16x8*)&WT[bcol*DIM + ks*32 + g4*8];
                acc = __builtin_amdgcn_mfma_f32_16x16x32_bf16(Af[ks], bF, acc, 0, 0, 0);
            }
            #pragma unroll
            for (int r = 0; r < 4; r++){
                int rw = r0 + g4*4 + r;
                if (rw < NSLOT) xWr[(size_t)rw*DIM + bcol] = acc[r];
            }
        }
        return;
    }
    int base_gw = bx*16;
    int tg = base_gw >> 10;
    int g = tg % 3;
    const float* as = (g==1) ? asc : asp;
    const float* ad = (g==1) ? adc : adp;
    // aggregate 4 segments per wave
    for (int k = 0; k < 4; k++){
        int segi = wib*4 + k;
        int gw = base_gw + segi;
        int slot = gw & (NSLOT-1);
        int n = cnt[gw]; if (n > SEGCAP) n = SEGCAP;
        const int* lst = csr + (size_t)gw*SEGCAP;
        int src0 = (lane < n) ? lst[lane] : 0;
        int src1 = (64+lane < n) ? lst[64+lane] : 0;
        int n0 = n < 64 ? n : 64;
        float w0, w1, wself = 0.f, scale;
        int v = -1;
        if (g == 2){
            w0 = (lane < n) ? 1.f : 0.f;
            w1 = (64+lane < n) ? 1.f : 0.f;
            scale = 1.f / (float)(n > 0 ? n : 1);
        } else {
            v = s[slot];
            float adv = ad[v];
            float eself = lrelu(as[v] + adv);
            float e0 = (lane < n)    ? lrelu(as[src0]+adv) : -3e38f;
            float e1 = (64+lane < n) ? lrelu(as[src1]+adv) : -3e38f;
            float m = fmaxf(eself, fmaxf(e0, e1));
            #pragma unroll
            for (int off = 32; off; off >>= 1) m = fmaxf(m, __shfl_xor(m, off));
            w0 = (lane < n)    ? __expf(e0 - m) : 0.f;
            w1 = (64+lane < n) ? __expf(e1 - m) : 0.f;
            float ds = w0 + w1;
            #pragma unroll
            for (int off = 32; off; off >>= 1) ds += __shfl_xor(ds, off);
            wself = __expf(eself - m);
            scale = 1.f / (wself + ds);
        }
        float a0 = 0.f, a1 = 0.f;
        int j = 0;
        for (; j+7 < n0; j += 8){
            int   si[8]; float qi[8]; unsigned ki[8];
            #pragma unroll
            for (int u = 0; u < 8; u++){ si[u] = __shfl(src0, j+u); qi[u] = __shfl(w0, j+u); }
            #pragma unroll
            for (int u = 0; u < 8; u++) ki[u] = Xbf[(size_t)si[u]*64 + lane];
            #pragma unroll
            for (int u = 0; u < 8; u++){ a0 += qi[u]*blo(ki[u]); a1 += qi[u]*bhi(ki[u]); }
        }
        for (; j+3 < n0; j += 4){
            int s0=__shfl(src0,j), s1=__shfl(src0,j+1), s2=__shfl(src0,j+2), s3=__shfl(src0,j+3);
            float q0=__shfl(w0,j), q1=__shfl(w0,j+1), q2=__shfl(w0,j+2), q3=__shfl(w0,j+3);
            unsigned k0=Xbf[(size_t)s0*64+lane];
            unsigned k1=Xbf[(size_t)s1*64+lane];
            unsigned k2=Xbf[(size_t)s2*64+lane];
            unsigned k3=Xbf[(size_t)s3*64+lane];
            a0 += q0*blo(k0) + q1*blo(k1) + q2*blo(k2) + q3*blo(k3);
            a1 += q0*bhi(k0) + q1*bhi(k1) + q2*bhi(k2) + q3*bhi(k3);
        }
        for (; j < n0; j++){
            int sj=__shfl(src0,j);
            float qj=__shfl(w0,j);
            unsigned pk=Xbf[(size_t)sj*64+lane];
            a0 += qj*blo(pk); a1 += qj*bhi(pk);
        }
        for (j = 64; j < n; j++){
            int sj=__shfl(src1,j-64);
            float qj=__shfl(w1,j-64);
            unsigned pk=Xbf[(size_t)sj*64+lane];
            a0 += qj*blo(pk); a1 += qj*bhi(pk);
        }
        if (g < 2){
            unsigned pk = Xbf[(size_t)v*64 + lane];
            a0 += wself*blo(pk); a1 += wself*bhi(pk);
        }
        tile[segi][lane] = (unsigned)f2b(a0*scale) | ((unsigned)f2b(a1*scale) << 16);
    }
    __syncthreads();
    // GEMM: 16 rows x 128 cols, wave wib does cols [wib*32, wib*32+32)
    const unsigned short* WT = WT4 + (size_t)g*DIM*DIM;
    int r = lane & 15, g4 = lane >> 4;
    bf16x8 Af[4];
    #pragma unroll
    for (int ks = 0; ks < 4; ks++)
        Af[ks] = *(const bf16x8*)&tile[r][ks*16 + g4*4];
    #pragma unroll
    for (int ct = 0; ct < 2; ct++){
        f32x4 acc = {0.f,0.f,0.f,0.f};
        int bcol = wib*32 + ct*16 + r;
        #pragma unroll
        for (int ks = 0; ks < 4; ks++){
            bf16x8 bF = *(const bf16x8*)&WT[bcol*DIM + ks*32 + g4*8];
            acc = __builtin_amdgcn_mfma_f32_16x16x32_bf16(Af[ks], bF, acc, 0, 0, 0);
        }
        #pragma unroll
        for (int rr = 0; rr < 4; rr++){
            int segrow = g4*4 + rr;
            aggOut[(size_t)(base_gw + segrow)*DIM + bcol] = acc[rr];
        }
    }
}

__global__ void k_gather(const int* __restrict__ rep,
                         const float* __restrict__ aggOut, const float* __restrict__ xWr,
                         const float* __restrict__ bp, const float* __restrict__ bc,
                         const float* __restrict__ bl, const float* __restrict__ br,
                         float* __restrict__ out){
    int i = blockIdx.x*blockDim.x + threadIdx.x;
    if (i >= NT*NSLOT*DIM) return;
    int d = i & 127;
    int r = (i >> 7) & (NSLOT-1);
    int t = i >> 17;
    int rp = rep[r];
    size_t base = ((size_t)(t*3)*NSLOT + rp)*DIM + d;
    out[i] = (aggOut[base] + aggOut[base + NSLOT*DIM] + aggOut[base + 2*NSLOT*DIM]
              + xWr[(size_t)rp*DIM + d]
              + bp[d] + bc[d] + bl[d] + br[d]) * (1.f/3.f);
}

extern "C" void kernel_launch(void* const* d_in, const int* in_sizes, int n_in,
                              void* d_out, int out_size, void* d_ws, size_t ws_size,
                              hipStream_t stream) {
    const int*   s    = (const int*)d_in[0];
    const int*   EI   = (const int*)d_in[3];
    const float* X    = (const float*)d_in[4];
    const float* Wp   = (const float*)d_in[5];
    const float* aspv = (const float*)d_in[6];
    const float* adpv = (const float*)d_in[7];
    const float* bp   = (const float*)d_in[8];
    const float* Wc   = (const float*)d_in[9];
    const float* ascv = (const float*)d_in[10];
    const float* adcv = (const float*)d_in[11];
    const float* bc   = (const float*)d_in[12];
    const float* Wl   = (const float*)d_in[13];
    const float* bl   = (const float*)d_in[14];
    const float* Wr   = (const float*)d_in[15];
    const float* br   = (const float*)d_in[16];
    float* out = (float*)d_out;

    char* w = (char*)d_ws;
    unsigned* Xbf = (unsigned*)w; w += (size_t)NN*64*4;
    unsigned short* WT4 = (unsigned short*)w; w += (size_t)4*DIM*DIM*2;
    float* wa  = (float*)w; w += (size_t)4*DIM*4;
    float* asp = (float*)w; w += (size_t)NN*4;
    float* adp = (float*)w; w += (size_t)NN*4;
    float* asc = (float*)w; w += (size_t)NN*4;
    float* adc = (float*)w; w += (size_t)NN*4;
    unsigned* bm = (unsigned*)w; w += (size_t)((NBM+3)&~3)*4;
    unsigned* hmap = (unsigned*)w; w += (size_t)HB*4;
    int* rep  = (int*)w; w += (size_t)NSLOT*4;
    int* cnt  = (int*)w; w += (size_t)NSEG*4;
    int* csr  = (int*)w; w += (size_t)NSEG*SEGCAP*4;
    float* aggOut = (float*)w; w += (size_t)NSEG*DIM*4;
    float* xWr = (float*)w; w += (size_t)NSLOT*DIM*4;

    k_prep      <<<13, 256, 0, stream>>>(Wp, Wc, Wl, Wr, aspv, adpv, ascv, adcv,
                                         s, bm, hmap, rep, cnt, wa, WT4);
    k_castbuild <<<NCAST+NBUILD, 256, 0, stream>>>(X, wa, Xbf, asp, adp, asc, adc,
                                                   EI, bm, hmap, cnt, csr);
    k_aggemm    <<<NAGG+16, 256, 0, stream>>>(Xbf, asp, adp, asc, adc, s, cnt, csr,
                                              WT4, aggOut, xWr);
    k_gather    <<<NT*NSLOT*DIM/256, 256, 0, stream>>>(rep, aggOut, xWr, bp, bc, bl, br, out);
}